// Round 1
// baseline (1508.532 us; speedup 1.0000x reference)
//
#include <hip/hip_runtime.h>
#include <hip/hip_bf16.h>
#include <stdint.h>
#include <string.h>

#define NNODES 16384
#define GIN 256      // input feature dim
#define NG 64        // nodes per graph (N/G)
#define NGRAPH 256
#define FDIM 64      // per-head out dim
#define CDIM 512     // H*F

__device__ __forceinline__ float bf2f(unsigned short u){
  union { unsigned int i; float f; } w; w.i = ((unsigned int)u) << 16; return w.f;
}

// ---------- dtype detection: fp32 low-halves look like garbage bf16 ----------
__global__ void k_detect(const unsigned short* __restrict__ x, int* __restrict__ flag){
  int lane = threadIdx.x;  // 64 threads
  int bad = 0;
  #pragma unroll
  for (int j = 0; j < 4; j++){
    float f = bf2f(x[lane*4 + j]);
    if (!(fabsf(f) < 1e4f)) bad++;   // catches huge and NaN
  }
  #pragma unroll
  for (int o = 32; o; o >>= 1) bad += __shfl_down(bad, o);
  if (lane == 0) *flag = (bad > 16) ? 1 : 0;   // 1 = inputs are fp32
}

// ---------- convert all float inputs to canonical fp32 in ws ----------
struct CArgs {
  const void* p[24];
  int cum[25];
};

__global__ void k_convert(CArgs a, const int* __restrict__ flag, float* __restrict__ dst, int total){
  int isf32 = *flag;
  for (int idx = blockIdx.x*blockDim.x + threadIdx.x; idx < total; idx += gridDim.x*blockDim.x){
    int seg = 0;
    while (idx >= a.cum[seg+1]) seg++;
    int off = idx - a.cum[seg];
    float v;
    if (isf32) v = ((const float*)a.p[seg])[off];
    else       v = bf2f(((const unsigned short*)a.p[seg])[off]);
    dst[idx] = v;
  }
}

// ---------- CSR build (by dst) ----------
__global__ void k_count(const int* __restrict__ edst, int E, int* __restrict__ deg){
  int e = blockIdx.x*blockDim.x + threadIdx.x;
  if (e < E) atomicAdd(&deg[edst[e]], 1);
}

__global__ void k_scan(const int* __restrict__ deg, int* __restrict__ off, int* __restrict__ cur){
  // one block, 256 threads, N = 16384 = 256*64
  __shared__ int ss[256];
  int t = threadIdx.x;
  int base = t * 64;
  int s = 0;
  for (int j = 0; j < 64; j++) s += deg[base + j];
  ss[t] = s;
  __syncthreads();
  for (int o = 1; o < 256; o <<= 1){
    int v = 0;
    if (t >= o) v = ss[t - o];
    __syncthreads();
    if (t >= o) ss[t] += v;
    __syncthreads();
  }
  int run = ss[t] - s;  // exclusive prefix
  for (int j = 0; j < 64; j++){
    int i = base + j;
    off[i] = run;
    cur[i] = run;
    run += deg[i];
  }
  if (t == 255) off[NNODES] = run;
}

__global__ void k_fill(const int* __restrict__ edst, int E, int* __restrict__ cur, int* __restrict__ eidl){
  int e = blockIdx.x*blockDim.x + threadIdx.x;
  if (e < E){
    int pos = atomicAdd(&cur[edst[e]], 1);
    eidl[pos] = e;
  }
}

// ---------- fp32 tiled GEMM: C[N x 512] = A[N x K] * W[K x 512], both Wl and Wr via grid.z ----------
__global__ __launch_bounds__(256) void k_gemm_dual(
    const float* __restrict__ A, const float* __restrict__ Wl, const float* __restrict__ Wr,
    float* __restrict__ Cl, float* __restrict__ Cr, int K){
  const float* W = blockIdx.z ? Wr : Wl;
  float*       C = blockIdx.z ? Cr : Cl;
  __shared__ float As[16][128];
  __shared__ float Bs[16][128];
  int tid = threadIdx.x;
  int tx = tid & 15, ty = tid >> 4;
  int row0 = blockIdx.x * 128, col0 = blockIdx.y * 128;

  float acc[8][8];
  #pragma unroll
  for (int i = 0; i < 8; i++)
    #pragma unroll
    for (int j = 0; j < 8; j++) acc[i][j] = 0.f;

  int ar = tid >> 1, akb = (tid & 1) * 8;
  const float* ap = A + (long)(row0 + ar) * K + akb;
  int bk = tid >> 4, bc = (tid & 15) * 8;
  const float* bp = W + (long)bk * CDIM + col0 + bc;

  for (int k0 = 0; k0 < K; k0 += 16){
    float4 a0 = *(const float4*)(ap + k0);
    float4 a1 = *(const float4*)(ap + k0 + 4);
    float4 b0 = *(const float4*)(bp + (long)k0 * CDIM);
    float4 b1 = *(const float4*)(bp + (long)k0 * CDIM + 4);
    As[akb+0][ar] = a0.x; As[akb+1][ar] = a0.y; As[akb+2][ar] = a0.z; As[akb+3][ar] = a0.w;
    As[akb+4][ar] = a1.x; As[akb+5][ar] = a1.y; As[akb+6][ar] = a1.z; As[akb+7][ar] = a1.w;
    *(float4*)&Bs[bk][bc]     = b0;
    *(float4*)&Bs[bk][bc + 4] = b1;
    __syncthreads();
    #pragma unroll
    for (int kk = 0; kk < 16; kk++){
      float4 a0v = *(const float4*)&As[kk][ty*8];
      float4 a1v = *(const float4*)&As[kk][ty*8 + 4];
      float4 b0v = *(const float4*)&Bs[kk][tx*8];
      float4 b1v = *(const float4*)&Bs[kk][tx*8 + 4];
      float av[8] = {a0v.x,a0v.y,a0v.z,a0v.w,a1v.x,a1v.y,a1v.z,a1v.w};
      float bv[8] = {b0v.x,b0v.y,b0v.z,b0v.w,b1v.x,b1v.y,b1v.z,b1v.w};
      #pragma unroll
      for (int i = 0; i < 8; i++)
        #pragma unroll
        for (int j = 0; j < 8; j++)
          acc[i][j] = fmaf(av[i], bv[j], acc[i][j]);
    }
    __syncthreads();
  }

  #pragma unroll
  for (int i = 0; i < 8; i++){
    float* cp = C + (long)(row0 + ty*8 + i) * CDIM + col0 + tx*8;
    float4 o0 = {acc[i][0], acc[i][1], acc[i][2], acc[i][3]};
    float4 o1 = {acc[i][4], acc[i][5], acc[i][6], acc[i][7]};
    *(float4*)cp       = o0;
    *(float4*)(cp + 4) = o1;
  }
}

// ---------- edge logits: p = exp(logit), den[dst,h] += p (no max-shift; |logit| small) ----------
__global__ __launch_bounds__(256) void k_edge_logits(
    const float* __restrict__ XL, const float* __restrict__ XR, const float* __restrict__ att,
    const int* __restrict__ esrc, const int* __restrict__ edst,
    float* __restrict__ P, float* __restrict__ DEN, int E){
  int wave = threadIdx.x >> 6, lane = threadIdx.x & 63;
  int e = blockIdx.x * 4 + wave;
  if (e >= E) return;
  int s = esrc[e], d = edst[e];
  const float* xl = XL + (long)s * CDIM + lane;
  const float* xr = XR + (long)d * CDIM + lane;
  #pragma unroll
  for (int h = 0; h < 8; h++){
    float m  = xl[h*64] + xr[h*64];
    float ee = m > 0.f ? m : 0.2f * m;        // leaky_relu(0.2)
    float v  = ee * att[h*64 + lane];
    #pragma unroll
    for (int o = 32; o; o >>= 1) v += __shfl_down(v, o);
    if (lane == 0){
      float p = expf(v);
      P[(long)e*8 + h] = p;
      atomicAdd(&DEN[d*8 + h], p);
    }
  }
}

// ---------- aggregation (concat layers 1,2): one wave per (dst, head) ----------
__global__ __launch_bounds__(256) void k_aggregate(
    const float* __restrict__ XL, const float* __restrict__ P, const float* __restrict__ DEN,
    const int* __restrict__ off, const int* __restrict__ eidl, const int* __restrict__ esrc,
    const float* __restrict__ bias, float* __restrict__ OUT){
  int wave = threadIdx.x >> 6, lane = threadIdx.x & 63;
  int gi = blockIdx.x * 4 + wave;
  if (gi >= NNODES * 8) return;
  int d = gi >> 3, h = gi & 7;
  int beg = off[d], end = off[d+1];
  float inv = 1.f / (DEN[d*8 + h] + 1e-16f);
  float acc = 0.f;
  for (int i = beg; i < end; i++){
    int eid = eidl[i];
    int s = esrc[eid];
    float alpha = P[(long)eid*8 + h] * inv;
    acc = fmaf(alpha, XL[(long)s*CDIM + h*64 + lane], acc);
  }
  OUT[(long)d*CDIM + h*64 + lane] = acc + bias[h*64 + lane];
}

// ---------- aggregation (mean over heads, layer 3): one wave per dst ----------
__global__ __launch_bounds__(256) void k_aggregate3(
    const float* __restrict__ XL, const float* __restrict__ P, const float* __restrict__ DEN,
    const int* __restrict__ off, const int* __restrict__ eidl, const int* __restrict__ esrc,
    const float* __restrict__ bias, float* __restrict__ OUT){
  int wave = threadIdx.x >> 6, lane = threadIdx.x & 63;
  int d = blockIdx.x * 4 + wave;
  if (d >= NNODES) return;
  int beg = off[d], end = off[d+1];
  float accm = 0.f;
  for (int h = 0; h < 8; h++){
    float inv = 1.f / (DEN[d*8 + h] + 1e-16f);
    float acc = 0.f;
    for (int i = beg; i < end; i++){
      int eid = eidl[i];
      int s = esrc[eid];
      acc = fmaf(P[(long)eid*8 + h], XL[(long)s*CDIM + h*64 + lane], acc);
    }
    accm = fmaf(acc, inv, accm);
  }
  OUT[(long)d*FDIM + lane] = accm * 0.125f + bias[lane];
}

// ---------- GraphNorm + ReLU (nodes of graph g are rows g*64 .. g*64+63) ----------
__global__ void k_graphnorm_relu(const float* __restrict__ X, const float* __restrict__ w,
    const float* __restrict__ b, const float* __restrict__ ms,
    float* __restrict__ Y, int C){
  int g = blockIdx.x;
  const float* xg = X + (long)g * NG * C;
  float*       yg = Y + (long)g * NG * C;
  for (int c = threadIdx.x; c < C; c += blockDim.x){
    float s1 = 0.f, s2 = 0.f;
    for (int i = 0; i < NG; i++){
      float v = xg[(long)i*C + c];
      s1 += v; s2 += v*v;
    }
    float mean = s1 * (1.f/NG);
    float m = ms[c];
    // var = E[(x - m*mean)^2] = E[x^2] - 2*m*mean*E[x] + m^2*mean^2
    float var = s2 * (1.f/NG) - 2.f*m*mean*mean + m*m*mean*mean;
    float inv = rsqrtf(var + 1e-5f);
    float ww = w[c], bb = b[c];
    for (int i = 0; i < NG; i++){
      float v = xg[(long)i*C + c];
      float y = fmaf(ww * (v - m*mean), inv, bb);
      yg[(long)i*C + c] = y > 0.f ? y : 0.f;
    }
  }
}

// ---------- global mean pool + linear [64 -> 2], dtype-flag-aware output ----------
__global__ void k_pool_linear(const float* __restrict__ H, const float* __restrict__ Wlin,
    const float* __restrict__ blin, void* out, const int* __restrict__ flag){
  int g = blockIdx.x, c = threadIdx.x;  // 64 threads
  float s = 0.f;
  for (int i = 0; i < NG; i++) s += H[(long)(g*NG + i)*FDIM + c];
  float pooled = s * (1.f/NG);
  float v0 = pooled * Wlin[c*2 + 0];
  float v1 = pooled * Wlin[c*2 + 1];
  #pragma unroll
  for (int o = 32; o; o >>= 1){ v0 += __shfl_down(v0, o); v1 += __shfl_down(v1, o); }
  if (c == 0){
    float o0 = v0 + blin[0], o1 = v1 + blin[1];
    if (*flag){
      ((float*)out)[g*2 + 0] = o0;
      ((float*)out)[g*2 + 1] = o1;
    } else {
      ((__hip_bfloat16*)out)[g*2 + 0] = __float2bfloat16(o0);
      ((__hip_bfloat16*)out)[g*2 + 1] = __float2bfloat16(o1);
    }
  }
}

extern "C" void kernel_launch(void* const* d_in, const int* in_sizes, int n_in,
                              void* d_out, int out_size, void* d_ws, size_t ws_size,
                              hipStream_t stream){
  const int N = NNODES;
  const int E = in_sizes[1];

  const int* esrc = (const int*)d_in[1];
  const int* edst = (const int*)d_in[2];

  // ---- workspace layout ----
  char* ws = (char*)d_ws;
  size_t cursor_b = 0;
  auto alloc = [&](size_t bytes)->char*{
    char* p = ws + cursor_b;
    cursor_b += (bytes + 255) & ~size_t(255);
    return p;
  };

  int* flag = (int*)alloc(256);

  // conversion segments: x + all float weights, in input order
  static const int convIdx[24] = {0,4,5,6,7,8,9,10,11,12,13,14,15,16,17,18,19,20,21,22,23,24,25,26};
  CArgs ca;
  int cums[25]; cums[0] = 0;
  for (int i = 0; i < 24; i++){
    ca.p[i] = d_in[convIdx[i]];
    cums[i+1] = cums[i] + in_sizes[convIdx[i]];
  }
  memcpy(ca.cum, cums, sizeof(cums));
  int totalConv = cums[24];

  float* conv = (float*)alloc((size_t)totalConv * 4);
  const float* fv[24];
  for (int i = 0; i < 24; i++) fv[i] = conv + cums[i];
  // fv map: 0:x 1:Wl1 2:Wr1 3:att1 4:b1 5:gnw1 6:gnb1 7:gnm1
  //         8:Wl2 9:Wr2 10:att2 11:b2 12:gnw2 13:gnb2 14:gnm2
  //         15:Wl3 16:Wr3 17:att3 18:b3 19:gnw3 20:gnb3 21:gnm3 22:Wlin 23:blin

  float* XL  = (float*)alloc((size_t)N * CDIM * 4);
  float* XR  = (float*)alloc((size_t)N * CDIM * 4);   // also reused as OUT (pre-norm)
  float* HB  = (float*)alloc((size_t)N * CDIM * 4);   // normed output -> next layer input
  float* P   = (float*)alloc((size_t)E * 8 * 4);
  float* DEN = (float*)alloc((size_t)N * 8 * 4);
  int* deg  = (int*)alloc((size_t)N * 4);
  int* off  = (int*)alloc((size_t)(N + 1) * 4);
  int* cur  = (int*)alloc((size_t)N * 4);
  int* eidl = (int*)alloc((size_t)E * 4);
  float* OUT = XR;  // aggregation output aliases XR (XR fully consumed by k_edge_logits)

  // ---- dtype detect + convert ----
  k_detect<<<1, 64, 0, stream>>>((const unsigned short*)d_in[0], flag);
  k_convert<<<2048, 256, 0, stream>>>(ca, flag, conv, totalConv);

  // ---- CSR by dst ----
  hipMemsetAsync(deg, 0, (size_t)N * 4, stream);
  k_count<<<(E + 255)/256, 256, 0, stream>>>(edst, E, deg);
  k_scan<<<1, 256, 0, stream>>>(deg, off, cur);
  k_fill<<<(E + 255)/256, 256, 0, stream>>>(edst, E, cur, eidl);

  // ---- 3 GATv2 + GraphNorm + ReLU layers ----
  const float* Wl_[3]  = {fv[1],  fv[8],  fv[15]};
  const float* Wr_[3]  = {fv[2],  fv[9],  fv[16]};
  const float* att_[3] = {fv[3],  fv[10], fv[17]};
  const float* b_[3]   = {fv[4],  fv[11], fv[18]};
  const float* gw_[3]  = {fv[5],  fv[12], fv[19]};
  const float* gb_[3]  = {fv[6],  fv[13], fv[20]};
  const float* gm_[3]  = {fv[7],  fv[14], fv[21]};

  const float* inbuf = fv[0];  // converted x
  int K = GIN;
  for (int layer = 0; layer < 3; layer++){
    k_gemm_dual<<<dim3(N/128, CDIM/128, 2), 256, 0, stream>>>(inbuf, Wl_[layer], Wr_[layer], XL, XR, K);
    hipMemsetAsync(DEN, 0, (size_t)N * 8 * 4, stream);
    k_edge_logits<<<(E + 3)/4, 256, 0, stream>>>(XL, XR, att_[layer], esrc, edst, P, DEN, E);
    if (layer < 2){
      k_aggregate<<<(N*8)/4, 256, 0, stream>>>(XL, P, DEN, off, eidl, esrc, b_[layer], OUT);
      k_graphnorm_relu<<<NGRAPH, 256, 0, stream>>>(OUT, gw_[layer], gb_[layer], gm_[layer], HB, CDIM);
    } else {
      k_aggregate3<<<N/4, 256, 0, stream>>>(XL, P, DEN, off, eidl, esrc, b_[layer], OUT);
      k_graphnorm_relu<<<NGRAPH, 64, 0, stream>>>(OUT, gw_[layer], gb_[layer], gm_[layer], HB, FDIM);
    }
    inbuf = HB;
    K = CDIM;
  }

  // ---- pool + linear ----
  k_pool_linear<<<NGRAPH, 64, 0, stream>>>(HB, fv[22], fv[23], d_out, flag);
}

// Round 2
// 1166.301 us; speedup vs baseline: 1.2934x; 1.2934x over previous
//
#include <hip/hip_runtime.h>
#include <hip/hip_bf16.h>
#include <stdint.h>
#include <string.h>

#define NNODES 16384
#define GIN 256      // input feature dim
#define NG 64        // nodes per graph (N/G)
#define NGRAPH 256
#define FDIM 64      // per-head out dim
#define CDIM 512     // H*F

typedef __attribute__((ext_vector_type(8))) short bf16x8;
typedef __attribute__((ext_vector_type(4))) float f32x4;

__device__ __forceinline__ float bf2f(unsigned short u){
  union { unsigned int i; float f; } w; w.i = ((unsigned int)u) << 16; return w.f;
}

__device__ __forceinline__ void async16(const void* g, void* l){
  __builtin_amdgcn_global_load_lds(
      (const __attribute__((address_space(1))) unsigned int*)g,
      (__attribute__((address_space(3))) unsigned int*)l, 16, 0, 0);
}

// ---------- dtype detection: fp32 low-halves look like garbage bf16 ----------
__global__ void k_detect(const unsigned short* __restrict__ x, int* __restrict__ flag){
  int lane = threadIdx.x;  // 64 threads
  int bad = 0;
  #pragma unroll
  for (int j = 0; j < 4; j++){
    float f = bf2f(x[lane*4 + j]);
    if (!(fabsf(f) < 1e4f)) bad++;   // catches huge and NaN
  }
  #pragma unroll
  for (int o = 32; o; o >>= 1) bad += __shfl_down(bad, o);
  if (lane == 0) *flag = (bad > 16) ? 1 : 0;   // 1 = inputs are fp32
}

// ---------- convert all float inputs to canonical fp32 in ws ----------
struct CArgs {
  const void* p[24];
  int cum[25];
};

__global__ void k_convert(CArgs a, const int* __restrict__ flag, float* __restrict__ dst, int total){
  int isf32 = *flag;
  for (int idx = blockIdx.x*blockDim.x + threadIdx.x; idx < total; idx += gridDim.x*blockDim.x){
    int seg = 0;
    while (idx >= a.cum[seg+1]) seg++;
    int off = idx - a.cum[seg];
    float v;
    if (isf32) v = ((const float*)a.p[seg])[off];
    else       v = bf2f(((const unsigned short*)a.p[seg])[off]);
    dst[idx] = v;
  }
}

// ---------- fp32 -> bf16 elementwise ----------
__global__ void k_f2b(const float* __restrict__ src, __hip_bfloat16* __restrict__ dst, int n){
  for (int i = blockIdx.x*blockDim.x + threadIdx.x; i < n; i += gridDim.x*blockDim.x)
    dst[i] = __float2bfloat16(src[i]);
}

// ---------- W[K x 512] fp32 -> Wt[512 x K] bf16 (transpose) ----------
__global__ void k_transpose_bf(const float* __restrict__ W, __hip_bfloat16* __restrict__ Wt, int K){
  __shared__ float t[32][33];
  int n0 = blockIdx.x*32, k0 = blockIdx.y*32;
  for (int r = threadIdx.y; r < 32; r += 8)
    t[r][threadIdx.x] = W[(size_t)(k0 + r)*CDIM + n0 + threadIdx.x];
  __syncthreads();
  for (int r = threadIdx.y; r < 32; r += 8)
    Wt[(size_t)(n0 + r)*K + k0 + threadIdx.x] = __float2bfloat16(t[threadIdx.x][r]);
}

// ---------- CSR build (by dst) ----------
__global__ void k_count(const int* __restrict__ edst, int E, int* __restrict__ deg){
  int e = blockIdx.x*blockDim.x + threadIdx.x;
  if (e < E) atomicAdd(&deg[edst[e]], 1);
}

__global__ void k_scan(const int* __restrict__ deg, int* __restrict__ off, int* __restrict__ cur){
  __shared__ int ss[256];
  int t = threadIdx.x;
  int base = t * 64;
  int s = 0;
  for (int j = 0; j < 64; j++) s += deg[base + j];
  ss[t] = s;
  __syncthreads();
  for (int o = 1; o < 256; o <<= 1){
    int v = 0;
    if (t >= o) v = ss[t - o];
    __syncthreads();
    if (t >= o) ss[t] += v;
    __syncthreads();
  }
  int run = ss[t] - s;  // exclusive prefix
  for (int j = 0; j < 64; j++){
    int i = base + j;
    off[i] = run;
    cur[i] = run;
    run += deg[i];
  }
  if (t == 255) off[NNODES] = run;
}

__global__ void k_fill(const int* __restrict__ edst, int E, int* __restrict__ cur, int* __restrict__ eidl){
  int e = blockIdx.x*blockDim.x + threadIdx.x;
  if (e < E){
    int pos = atomicAdd(&cur[edst[e]], 1);
    eidl[pos] = e;
  }
}

// ---------- bf16 MFMA GEMM: C[N x 512] = A[N x K] * Wt^T, Wl and Wr via grid.z ----------
// m97-style: 128x128 tile, BK=32, global_load_lds width=16, LDS layout [k-octet][row]
__global__ __launch_bounds__(256) void k_gemm_mfma(
    const __hip_bfloat16* __restrict__ A,
    const __hip_bfloat16* __restrict__ Wtl, const __hip_bfloat16* __restrict__ Wtr,
    float* __restrict__ Cl, float* __restrict__ Cr, int K){
  const __hip_bfloat16* Wt = blockIdx.z ? Wtr : Wtl;
  float*                C  = blockIdx.z ? Cr  : Cl;
  __shared__ __align__(16) char As[8192];  // [c:4][m:128] 16B chunks
  __shared__ __align__(16) char Bs[8192];  // [c:4][n:128] 16B chunks
  int tid = threadIdx.x;
  int w = tid >> 6, lane = tid & 63;
  int wm = w >> 1, wn = w & 1;
  int row0 = blockIdx.x * 128, col0 = blockIdx.y * 128;
  int c = lane >> 4, l16 = lane & 15;

  f32x4 acc[4][4];
  #pragma unroll
  for (int i = 0; i < 4; i++)
    #pragma unroll
    for (int j = 0; j < 4; j++) acc[i][j] = (f32x4){0.f,0.f,0.f,0.f};

  for (int k0 = 0; k0 < K; k0 += 32){
    // stage: 8 A-calls + 8 B-calls, 4 per wave, 1024B each
    #pragma unroll
    for (int t = 0; t < 4; t++){
      int call = t*4 + w;             // wave-uniform
      if (call < 8){
        int cc = call >> 1, half = call & 1;
        const __hip_bfloat16* gp = A + (size_t)(row0 + half*64 + lane)*K + k0 + cc*8;
        async16(gp, As + call*1024);
      } else {
        int q = call - 8;
        int cc = q >> 1, half = q & 1;
        const __hip_bfloat16* gp = Wt + (size_t)(col0 + half*64 + lane)*K + k0 + cc*8;
        async16(gp, Bs + q*1024);
      }
    }
    __syncthreads();
    bf16x8 af[4], bfr[4];
    #pragma unroll
    for (int i = 0; i < 4; i++)
      af[i]  = *(const bf16x8*)(As + c*2048 + (wm*64 + i*16 + l16)*16);
    #pragma unroll
    for (int j = 0; j < 4; j++)
      bfr[j] = *(const bf16x8*)(Bs + c*2048 + (wn*64 + j*16 + l16)*16);
    #pragma unroll
    for (int i = 0; i < 4; i++)
      #pragma unroll
      for (int j = 0; j < 4; j++)
        acc[i][j] = __builtin_amdgcn_mfma_f32_16x16x32_bf16(af[i], bfr[j], acc[i][j], 0, 0, 0);
    __syncthreads();
  }

  // epilogue: C/D layout col=lane&15, row=(lane>>4)*4+reg
  int r4 = lane >> 4;
  #pragma unroll
  for (int i = 0; i < 4; i++)
    #pragma unroll
    for (int j = 0; j < 4; j++){
      float* cp = C + (size_t)(row0 + wm*64 + i*16 + r4*4)*CDIM + col0 + wn*64 + j*16 + l16;
      #pragma unroll
      for (int r = 0; r < 4; r++)
        cp[(size_t)r*CDIM] = acc[i][j][r];
    }
}

// ---------- edge logits: p = exp(logit), den[dst,h] += p (no max-shift; |logit| small) ----------
__global__ __launch_bounds__(256) void k_edge_logits(
    const float* __restrict__ XL, const float* __restrict__ XR, const float* __restrict__ att,
    const int* __restrict__ esrc, const int* __restrict__ edst,
    float* __restrict__ P, float* __restrict__ DEN, int E){
  int wave = threadIdx.x >> 6, lane = threadIdx.x & 63;
  int e = blockIdx.x * 4 + wave;
  if (e >= E) return;
  int s = esrc[e], d = edst[e];
  const float* xl = XL + (long)s * CDIM + lane;
  const float* xr = XR + (long)d * CDIM + lane;
  #pragma unroll
  for (int h = 0; h < 8; h++){
    float m  = xl[h*64] + xr[h*64];
    float ee = m > 0.f ? m : 0.2f * m;        // leaky_relu(0.2)
    float v  = ee * att[h*64 + lane];
    #pragma unroll
    for (int o = 32; o; o >>= 1) v += __shfl_down(v, o);
    if (lane == 0){
      float p = expf(v);
      P[(long)e*8 + h] = p;
      atomicAdd(&DEN[d*8 + h], p);
    }
  }
}

// ---------- aggregation (concat layers 1,2): one wave per (dst, head) ----------
__global__ __launch_bounds__(256) void k_aggregate(
    const float* __restrict__ XL, const float* __restrict__ P, const float* __restrict__ DEN,
    const int* __restrict__ off, const int* __restrict__ eidl, const int* __restrict__ esrc,
    const float* __restrict__ bias, float* __restrict__ OUT){
  int wave = threadIdx.x >> 6, lane = threadIdx.x & 63;
  int gi = blockIdx.x * 4 + wave;
  if (gi >= NNODES * 8) return;
  int d = gi >> 3, h = gi & 7;
  int beg = off[d], end = off[d+1];
  float inv = 1.f / (DEN[d*8 + h] + 1e-16f);
  float acc = 0.f;
  for (int i = beg; i < end; i++){
    int eid = eidl[i];
    int s = esrc[eid];
    float alpha = P[(long)eid*8 + h] * inv;
    acc = fmaf(alpha, XL[(long)s*CDIM + h*64 + lane], acc);
  }
  OUT[(long)d*CDIM + h*64 + lane] = acc + bias[h*64 + lane];
}

// ---------- aggregation (mean over heads, layer 3): one wave per dst ----------
__global__ __launch_bounds__(256) void k_aggregate3(
    const float* __restrict__ XL, const float* __restrict__ P, const float* __restrict__ DEN,
    const int* __restrict__ off, const int* __restrict__ eidl, const int* __restrict__ esrc,
    const float* __restrict__ bias, float* __restrict__ OUT){
  int wave = threadIdx.x >> 6, lane = threadIdx.x & 63;
  int d = blockIdx.x * 4 + wave;
  if (d >= NNODES) return;
  int beg = off[d], end = off[d+1];
  float accm = 0.f;
  for (int h = 0; h < 8; h++){
    float inv = 1.f / (DEN[d*8 + h] + 1e-16f);
    float acc = 0.f;
    for (int i = beg; i < end; i++){
      int eid = eidl[i];
      int s = esrc[eid];
      acc = fmaf(P[(long)eid*8 + h], XL[(long)s*CDIM + h*64 + lane], acc);
    }
    accm = fmaf(acc, inv, accm);
  }
  OUT[(long)d*FDIM + lane] = accm * 0.125f + bias[lane];
}

// ---------- GraphNorm + ReLU -> bf16 (nodes of graph g are rows g*64 .. g*64+63) ----------
__global__ void k_graphnorm_relu(const float* __restrict__ X, const float* __restrict__ w,
    const float* __restrict__ b, const float* __restrict__ ms,
    __hip_bfloat16* __restrict__ Y, int C){
  int g = blockIdx.x;
  const float* xg = X + (long)g * NG * C;
  __hip_bfloat16* yg = Y + (long)g * NG * C;
  for (int c = threadIdx.x; c < C; c += blockDim.x){
    float s1 = 0.f, s2 = 0.f;
    for (int i = 0; i < NG; i++){
      float v = xg[(long)i*C + c];
      s1 += v; s2 += v*v;
    }
    float mean = s1 * (1.f/NG);
    float m = ms[c];
    float var = s2 * (1.f/NG) - 2.f*m*mean*mean + m*m*mean*mean;
    float inv = rsqrtf(var + 1e-5f);
    float ww = w[c], bb = b[c];
    for (int i = 0; i < NG; i++){
      float v = xg[(long)i*C + c];
      float y = fmaf(ww * (v - m*mean), inv, bb);
      yg[(long)i*C + c] = __float2bfloat16(y > 0.f ? y : 0.f);
    }
  }
}

// ---------- global mean pool + linear [64 -> 2], dtype-flag-aware output ----------
__global__ void k_pool_linear(const __hip_bfloat16* __restrict__ H, const float* __restrict__ Wlin,
    const float* __restrict__ blin, void* out, const int* __restrict__ flag){
  int g = blockIdx.x, c = threadIdx.x;  // 64 threads
  float s = 0.f;
  for (int i = 0; i < NG; i++) s += __bfloat162float(H[(long)(g*NG + i)*FDIM + c]);
  float pooled = s * (1.f/NG);
  float v0 = pooled * Wlin[c*2 + 0];
  float v1 = pooled * Wlin[c*2 + 1];
  #pragma unroll
  for (int o = 32; o; o >>= 1){ v0 += __shfl_down(v0, o); v1 += __shfl_down(v1, o); }
  if (c == 0){
    float o0 = v0 + blin[0], o1 = v1 + blin[1];
    if (*flag){
      ((float*)out)[g*2 + 0] = o0;
      ((float*)out)[g*2 + 1] = o1;
    } else {
      ((__hip_bfloat16*)out)[g*2 + 0] = __float2bfloat16(o0);
      ((__hip_bfloat16*)out)[g*2 + 1] = __float2bfloat16(o1);
    }
  }
}

extern "C" void kernel_launch(void* const* d_in, const int* in_sizes, int n_in,
                              void* d_out, int out_size, void* d_ws, size_t ws_size,
                              hipStream_t stream){
  const int N = NNODES;
  const int E = in_sizes[1];

  const int* esrc = (const int*)d_in[1];
  const int* edst = (const int*)d_in[2];

  // ---- workspace layout ----
  char* ws = (char*)d_ws;
  size_t cursor_b = 0;
  auto alloc = [&](size_t bytes)->char*{
    char* p = ws + cursor_b;
    cursor_b += (bytes + 255) & ~size_t(255);
    return p;
  };

  int* flag = (int*)alloc(256);

  // conversion segments: x + all float weights, in input order
  static const int convIdx[24] = {0,4,5,6,7,8,9,10,11,12,13,14,15,16,17,18,19,20,21,22,23,24,25,26};
  CArgs ca;
  int cums[25]; cums[0] = 0;
  for (int i = 0; i < 24; i++){
    ca.p[i] = d_in[convIdx[i]];
    cums[i+1] = cums[i] + in_sizes[convIdx[i]];
  }
  memcpy(ca.cum, cums, sizeof(cums));
  int totalConv = cums[24];

  float* conv = (float*)alloc((size_t)totalConv * 4);
  const float* fv[24];
  for (int i = 0; i < 24; i++) fv[i] = conv + cums[i];
  // fv map: 0:x 1:Wl1 2:Wr1 3:att1 4:b1 5:gnw1 6:gnb1 7:gnm1
  //         8:Wl2 9:Wr2 10:att2 11:b2 12:gnw2 13:gnb2 14:gnm2
  //         15:Wl3 16:Wr3 17:att3 18:b3 19:gnw3 20:gnb3 21:gnm3 22:Wlin 23:blin

  float* XL  = (float*)alloc((size_t)N * CDIM * 4);
  float* XR  = (float*)alloc((size_t)N * CDIM * 4);   // aggregation OUT aliases XR
  __hip_bfloat16* HBbf = (__hip_bfloat16*)alloc((size_t)N * CDIM * 2);  // normed bf16 activations
  __hip_bfloat16* xbf  = (__hip_bfloat16*)alloc((size_t)N * GIN * 2);
  __hip_bfloat16* Wt[6];
  Wt[0] = (__hip_bfloat16*)alloc((size_t)CDIM * GIN * 2);   // Wl1^T
  Wt[1] = (__hip_bfloat16*)alloc((size_t)CDIM * GIN * 2);   // Wr1^T
  Wt[2] = (__hip_bfloat16*)alloc((size_t)CDIM * CDIM * 2);  // Wl2^T
  Wt[3] = (__hip_bfloat16*)alloc((size_t)CDIM * CDIM * 2);  // Wr2^T
  Wt[4] = (__hip_bfloat16*)alloc((size_t)CDIM * CDIM * 2);  // Wl3^T
  Wt[5] = (__hip_bfloat16*)alloc((size_t)CDIM * CDIM * 2);  // Wr3^T
  float* P   = (float*)alloc((size_t)E * 8 * 4);
  float* DEN = (float*)alloc((size_t)N * 8 * 4);
  int* deg  = (int*)alloc((size_t)N * 4);
  int* off  = (int*)alloc((size_t)(N + 1) * 4);
  int* cur  = (int*)alloc((size_t)N * 4);
  int* eidl = (int*)alloc((size_t)E * 4);
  float* OUT = XR;

  // ---- dtype detect + convert ----
  k_detect<<<1, 64, 0, stream>>>((const unsigned short*)d_in[0], flag);
  k_convert<<<2048, 256, 0, stream>>>(ca, flag, conv, totalConv);
  k_f2b<<<1024, 256, 0, stream>>>(fv[0], xbf, N * GIN);
  {
    const float* Ws[6] = {fv[1], fv[2], fv[8], fv[9], fv[15], fv[16]};
    const int    Ks[6] = {GIN, GIN, CDIM, CDIM, CDIM, CDIM};
    for (int i = 0; i < 6; i++)
      k_transpose_bf<<<dim3(CDIM/32, Ks[i]/32), dim3(32, 8), 0, stream>>>(Ws[i], Wt[i], Ks[i]);
  }

  // ---- CSR by dst ----
  hipMemsetAsync(deg, 0, (size_t)N * 4, stream);
  k_count<<<(E + 255)/256, 256, 0, stream>>>(edst, E, deg);
  k_scan<<<1, 256, 0, stream>>>(deg, off, cur);
  k_fill<<<(E + 255)/256, 256, 0, stream>>>(edst, E, cur, eidl);

  // ---- 3 GATv2 + GraphNorm + ReLU layers ----
  const float* att_[3] = {fv[3],  fv[10], fv[17]};
  const float* b_[3]   = {fv[4],  fv[11], fv[18]};
  const float* gw_[3]  = {fv[5],  fv[12], fv[19]};
  const float* gb_[3]  = {fv[6],  fv[13], fv[20]};
  const float* gm_[3]  = {fv[7],  fv[14], fv[21]};

  const __hip_bfloat16* inbuf = xbf;
  int K = GIN;
  for (int layer = 0; layer < 3; layer++){
    k_gemm_mfma<<<dim3(N/128, CDIM/128, 2), 256, 0, stream>>>(
        inbuf, Wt[layer*2], Wt[layer*2 + 1], XL, XR, K);
    hipMemsetAsync(DEN, 0, (size_t)N * 8 * 4, stream);
    k_edge_logits<<<(E + 3)/4, 256, 0, stream>>>(XL, XR, att_[layer], esrc, edst, P, DEN, E);
    if (layer < 2){
      k_aggregate<<<(N*8)/4, 256, 0, stream>>>(XL, P, DEN, off, eidl, esrc, b_[layer], OUT);
      k_graphnorm_relu<<<NGRAPH, 256, 0, stream>>>(OUT, gw_[layer], gb_[layer], gm_[layer], HBbf, CDIM);
    } else {
      k_aggregate3<<<N/4, 256, 0, stream>>>(XL, P, DEN, off, eidl, esrc, b_[layer], OUT);
      k_graphnorm_relu<<<NGRAPH, 64, 0, stream>>>(OUT, gw_[layer], gb_[layer], gm_[layer], HBbf, FDIM);
    }
    inbuf = HBbf;
    K = CDIM;
  }

  // ---- pool + linear ----
  k_pool_linear<<<NGRAPH, 64, 0, stream>>>(HBbf, fv[22], fv[23], d_out, flag);
}

// Round 3
// 610.482 us; speedup vs baseline: 2.4711x; 1.9105x over previous
//
#include <hip/hip_runtime.h>
#include <hip/hip_bf16.h>
#include <stdint.h>
#include <string.h>

#define NNODES 16384
#define GIN 256      // input feature dim
#define NG 64        // nodes per graph (N/G)
#define NGRAPH 256
#define FDIM 64      // per-head out dim
#define CDIM 512     // H*F

typedef __attribute__((ext_vector_type(8))) short bf16x8;
typedef __attribute__((ext_vector_type(4))) float f32x4;

__device__ __forceinline__ float bf2f(unsigned short u){
  union { unsigned int i; float f; } w; w.i = ((unsigned int)u) << 16; return w.f;
}

__device__ __forceinline__ void async16(const void* g, void* l){
  __builtin_amdgcn_global_load_lds(
      (const __attribute__((address_space(1))) unsigned int*)g,
      (__attribute__((address_space(3))) unsigned int*)l, 16, 0, 0);
}

// ---------- dtype detection: fp32 low-halves look like garbage bf16 ----------
__global__ void k_detect(const unsigned short* __restrict__ x, int* __restrict__ flag){
  int lane = threadIdx.x;  // 64 threads
  int bad = 0;
  #pragma unroll
  for (int j = 0; j < 4; j++){
    float f = bf2f(x[lane*4 + j]);
    if (!(fabsf(f) < 1e4f)) bad++;   // catches huge and NaN
  }
  #pragma unroll
  for (int o = 32; o; o >>= 1) bad += __shfl_down(bad, o);
  if (lane == 0) *flag = (bad > 16) ? 1 : 0;   // 1 = inputs are fp32
}

// ---------- convert all float inputs to canonical fp32 in ws ----------
struct CArgs {
  const void* p[24];
  int cum[25];
};

__global__ void k_convert(CArgs a, const int* __restrict__ flag, float* __restrict__ dst, int total){
  int isf32 = *flag;
  for (int idx = blockIdx.x*blockDim.x + threadIdx.x; idx < total; idx += gridDim.x*blockDim.x){
    int seg = 0;
    while (idx >= a.cum[seg+1]) seg++;
    int off = idx - a.cum[seg];
    float v;
    if (isf32) v = ((const float*)a.p[seg])[off];
    else       v = bf2f(((const unsigned short*)a.p[seg])[off]);
    dst[idx] = v;
  }
}

// ---------- fp32 -> bf16 elementwise ----------
__global__ void k_f2b(const float* __restrict__ src, __hip_bfloat16* __restrict__ dst, int n){
  for (int i = blockIdx.x*blockDim.x + threadIdx.x; i < n; i += gridDim.x*blockDim.x)
    dst[i] = __float2bfloat16(src[i]);
}

// ---------- W[K x 512] fp32 -> Wt[512 x K] bf16 (transpose) ----------
__global__ void k_transpose_bf(const float* __restrict__ W, __hip_bfloat16* __restrict__ Wt, int K){
  __shared__ float t[32][33];
  int n0 = blockIdx.x*32, k0 = blockIdx.y*32;
  for (int r = threadIdx.y; r < 32; r += 8)
    t[r][threadIdx.x] = W[(size_t)(k0 + r)*CDIM + n0 + threadIdx.x];
  __syncthreads();
  for (int r = threadIdx.y; r < 32; r += 8)
    Wt[(size_t)(n0 + r)*K + k0 + threadIdx.x] = __float2bfloat16(t[threadIdx.x][r]);
}

// ---------- CSR build (by dst), payload = src node ----------
__global__ void k_count(const int* __restrict__ edst, int E, int* __restrict__ deg){
  int e = blockIdx.x*blockDim.x + threadIdx.x;
  if (e < E) atomicAdd(&deg[edst[e]], 1);
}

__global__ void k_scan(const int* __restrict__ deg, int* __restrict__ off, int* __restrict__ cur){
  __shared__ int ss[256];
  int t = threadIdx.x;
  int base = t * 64;
  int s = 0;
  for (int j = 0; j < 64; j++) s += deg[base + j];
  ss[t] = s;
  __syncthreads();
  for (int o = 1; o < 256; o <<= 1){
    int v = 0;
    if (t >= o) v = ss[t - o];
    __syncthreads();
    if (t >= o) ss[t] += v;
    __syncthreads();
  }
  int run = ss[t] - s;  // exclusive prefix
  for (int j = 0; j < 64; j++){
    int i = base + j;
    off[i] = run;
    cur[i] = run;
    run += deg[i];
  }
  if (t == 255) off[NNODES] = run;
}

__global__ void k_fill(const int* __restrict__ esrc, const int* __restrict__ edst, int E,
                       int* __restrict__ cur, int* __restrict__ srcs){
  int e = blockIdx.x*blockDim.x + threadIdx.x;
  if (e < E){
    int pos = atomicAdd(&cur[edst[e]], 1);
    srcs[pos] = esrc[e];
  }
}

// ---------- bf16 MFMA GEMM: C[N x 512] = A[N x K] * Wt^T, Wl and Wr via grid.z ----------
__global__ __launch_bounds__(256) void k_gemm_mfma(
    const __hip_bfloat16* __restrict__ A,
    const __hip_bfloat16* __restrict__ Wtl, const __hip_bfloat16* __restrict__ Wtr,
    float* __restrict__ Cl, float* __restrict__ Cr, int K){
  const __hip_bfloat16* Wt = blockIdx.z ? Wtr : Wtl;
  float*                C  = blockIdx.z ? Cr  : Cl;
  __shared__ __align__(16) char As[8192];  // [c:4][m:128] 16B chunks
  __shared__ __align__(16) char Bs[8192];  // [c:4][n:128] 16B chunks
  int tid = threadIdx.x;
  int w = tid >> 6, lane = tid & 63;
  int wm = w >> 1, wn = w & 1;
  int row0 = blockIdx.x * 128, col0 = blockIdx.y * 128;
  int c = lane >> 4, l16 = lane & 15;

  f32x4 acc[4][4];
  #pragma unroll
  for (int i = 0; i < 4; i++)
    #pragma unroll
    for (int j = 0; j < 4; j++) acc[i][j] = (f32x4){0.f,0.f,0.f,0.f};

  for (int k0 = 0; k0 < K; k0 += 32){
    #pragma unroll
    for (int t = 0; t < 4; t++){
      int call = t*4 + w;             // wave-uniform
      if (call < 8){
        int cc = call >> 1, half = call & 1;
        const __hip_bfloat16* gp = A + (size_t)(row0 + half*64 + lane)*K + k0 + cc*8;
        async16(gp, As + call*1024);
      } else {
        int q = call - 8;
        int cc = q >> 1, half = q & 1;
        const __hip_bfloat16* gp = Wt + (size_t)(col0 + half*64 + lane)*K + k0 + cc*8;
        async16(gp, Bs + q*1024);
      }
    }
    __syncthreads();
    bf16x8 af[4], bfr[4];
    #pragma unroll
    for (int i = 0; i < 4; i++)
      af[i]  = *(const bf16x8*)(As + c*2048 + (wm*64 + i*16 + l16)*16);
    #pragma unroll
    for (int j = 0; j < 4; j++)
      bfr[j] = *(const bf16x8*)(Bs + c*2048 + (wn*64 + j*16 + l16)*16);
    #pragma unroll
    for (int i = 0; i < 4; i++)
      #pragma unroll
      for (int j = 0; j < 4; j++)
        acc[i][j] = __builtin_amdgcn_mfma_f32_16x16x32_bf16(af[i], bfr[j], acc[i][j], 0, 0, 0);
    __syncthreads();
  }

  int r4 = lane >> 4;
  #pragma unroll
  for (int i = 0; i < 4; i++)
    #pragma unroll
    for (int j = 0; j < 4; j++){
      float* cp = C + (size_t)(row0 + wm*64 + i*16 + r4*4)*CDIM + col0 + wn*64 + j*16 + l16;
      #pragma unroll
      for (int r = 0; r < 4; r++)
        cp[(size_t)r*CDIM] = acc[i][j][r];
    }
}

// ---------- fused GATv2 edge phase: logits + softmax + aggregate, one wave per dst ----------
// lane = feature f (0..63); 8 heads held in registers per lane.
template<int CONCAT>
__global__ __launch_bounds__(256) void k_fused_attn(
    const float* __restrict__ XL, const float* __restrict__ XR, const float* __restrict__ att,
    const int* __restrict__ off, const int* __restrict__ srcs,
    const float* __restrict__ bias, float* __restrict__ OUT){
  int wave = threadIdx.x >> 6, lane = threadIdx.x & 63;
  int d = blockIdx.x * 4 + wave;
  if (d >= NNODES) return;

  float xr[8], at[8], acc[8], den[8];
  const float* xrp = XR + (size_t)d*CDIM + lane;
  #pragma unroll
  for (int h = 0; h < 8; h++){
    xr[h]  = xrp[h*64];
    at[h]  = att[h*64 + lane];
    acc[h] = 0.f;
    den[h] = 0.f;
  }

  int beg = off[d], end = off[d+1];
  for (int i = beg; i < end; i++){
    int s = srcs[i];
    const float* xlp = XL + (size_t)s*CDIM + lane;
    float xv[8], v[8];
    #pragma unroll
    for (int h = 0; h < 8; h++) xv[h] = xlp[h*64];
    #pragma unroll
    for (int h = 0; h < 8; h++){
      float m = xv[h] + xr[h];
      float e = m > 0.f ? m : 0.2f * m;      // leaky_relu(0.2)
      v[h] = e * at[h];
    }
    // butterfly reduce over 64 lanes; all lanes end with the full sum
    #pragma unroll
    for (int o = 1; o < 64; o <<= 1)
      #pragma unroll
      for (int h = 0; h < 8; h++)
        v[h] += __shfl_xor(v[h], o);
    #pragma unroll
    for (int h = 0; h < 8; h++){
      float p = expf(v[h]);
      den[h] += p;
      acc[h] = fmaf(p, xv[h], acc[h]);
    }
  }

  if (CONCAT){
    float* op = OUT + (size_t)d*CDIM + lane;
    #pragma unroll
    for (int h = 0; h < 8; h++)
      op[h*64] = acc[h] / (den[h] + 1e-16f) + bias[h*64 + lane];
  } else {
    float s = 0.f;
    #pragma unroll
    for (int h = 0; h < 8; h++) s += acc[h] / (den[h] + 1e-16f);
    OUT[(size_t)d*FDIM + lane] = s * 0.125f + bias[lane];
  }
}

// ---------- GraphNorm + ReLU -> bf16 (nodes of graph g are rows g*64 .. g*64+63) ----------
__global__ void k_graphnorm_relu(const float* __restrict__ X, const float* __restrict__ w,
    const float* __restrict__ b, const float* __restrict__ ms,
    __hip_bfloat16* __restrict__ Y, int C){
  int g = blockIdx.x;
  const float* xg = X + (long)g * NG * C;
  __hip_bfloat16* yg = Y + (long)g * NG * C;
  for (int c = threadIdx.x; c < C; c += blockDim.x){
    float s1 = 0.f, s2 = 0.f;
    for (int i = 0; i < NG; i++){
      float v = xg[(long)i*C + c];
      s1 += v; s2 += v*v;
    }
    float mean = s1 * (1.f/NG);
    float m = ms[c];
    float var = s2 * (1.f/NG) - 2.f*m*mean*mean + m*m*mean*mean;
    float inv = rsqrtf(var + 1e-5f);
    float ww = w[c], bb = b[c];
    for (int i = 0; i < NG; i++){
      float v = xg[(long)i*C + c];
      float y = fmaf(ww * (v - m*mean), inv, bb);
      yg[(long)i*C + c] = __float2bfloat16(y > 0.f ? y : 0.f);
    }
  }
}

// ---------- global mean pool + linear [64 -> 2], dtype-flag-aware output ----------
__global__ void k_pool_linear(const __hip_bfloat16* __restrict__ H, const float* __restrict__ Wlin,
    const float* __restrict__ blin, void* out, const int* __restrict__ flag){
  int g = blockIdx.x, c = threadIdx.x;  // 64 threads
  float s = 0.f;
  for (int i = 0; i < NG; i++) s += __bfloat162float(H[(long)(g*NG + i)*FDIM + c]);
  float pooled = s * (1.f/NG);
  float v0 = pooled * Wlin[c*2 + 0];
  float v1 = pooled * Wlin[c*2 + 1];
  #pragma unroll
  for (int o = 32; o; o >>= 1){ v0 += __shfl_down(v0, o); v1 += __shfl_down(v1, o); }
  if (c == 0){
    float o0 = v0 + blin[0], o1 = v1 + blin[1];
    if (*flag){
      ((float*)out)[g*2 + 0] = o0;
      ((float*)out)[g*2 + 1] = o1;
    } else {
      ((__hip_bfloat16*)out)[g*2 + 0] = __float2bfloat16(o0);
      ((__hip_bfloat16*)out)[g*2 + 1] = __float2bfloat16(o1);
    }
  }
}

extern "C" void kernel_launch(void* const* d_in, const int* in_sizes, int n_in,
                              void* d_out, int out_size, void* d_ws, size_t ws_size,
                              hipStream_t stream){
  const int N = NNODES;
  const int E = in_sizes[1];

  const int* esrc = (const int*)d_in[1];
  const int* edst = (const int*)d_in[2];

  // ---- workspace layout ----
  char* ws = (char*)d_ws;
  size_t cursor_b = 0;
  auto alloc = [&](size_t bytes)->char*{
    char* p = ws + cursor_b;
    cursor_b += (bytes + 255) & ~size_t(255);
    return p;
  };

  int* flag = (int*)alloc(256);

  static const int convIdx[24] = {0,4,5,6,7,8,9,10,11,12,13,14,15,16,17,18,19,20,21,22,23,24,25,26};
  CArgs ca;
  int cums[25]; cums[0] = 0;
  for (int i = 0; i < 24; i++){
    ca.p[i] = d_in[convIdx[i]];
    cums[i+1] = cums[i] + in_sizes[convIdx[i]];
  }
  memcpy(ca.cum, cums, sizeof(cums));
  int totalConv = cums[24];

  float* conv = (float*)alloc((size_t)totalConv * 4);
  const float* fv[24];
  for (int i = 0; i < 24; i++) fv[i] = conv + cums[i];
  // fv map: 0:x 1:Wl1 2:Wr1 3:att1 4:b1 5:gnw1 6:gnb1 7:gnm1
  //         8:Wl2 9:Wr2 10:att2 11:b2 12:gnw2 13:gnb2 14:gnm2
  //         15:Wl3 16:Wr3 17:att3 18:b3 19:gnw3 20:gnb3 21:gnm3 22:Wlin 23:blin

  float* XL  = (float*)alloc((size_t)N * CDIM * 4);
  float* XR  = (float*)alloc((size_t)N * CDIM * 4);   // fused OUT aliases XR (row-local)
  __hip_bfloat16* HBbf = (__hip_bfloat16*)alloc((size_t)N * CDIM * 2);
  __hip_bfloat16* xbf  = (__hip_bfloat16*)alloc((size_t)N * GIN * 2);
  __hip_bfloat16* Wt[6];
  Wt[0] = (__hip_bfloat16*)alloc((size_t)CDIM * GIN * 2);
  Wt[1] = (__hip_bfloat16*)alloc((size_t)CDIM * GIN * 2);
  Wt[2] = (__hip_bfloat16*)alloc((size_t)CDIM * CDIM * 2);
  Wt[3] = (__hip_bfloat16*)alloc((size_t)CDIM * CDIM * 2);
  Wt[4] = (__hip_bfloat16*)alloc((size_t)CDIM * CDIM * 2);
  Wt[5] = (__hip_bfloat16*)alloc((size_t)CDIM * CDIM * 2);
  int* deg  = (int*)alloc((size_t)N * 4);
  int* off  = (int*)alloc((size_t)(N + 1) * 4);
  int* cur  = (int*)alloc((size_t)N * 4);
  int* srcs = (int*)alloc((size_t)E * 4);
  float* OUT = XR;

  // ---- dtype detect + convert ----
  k_detect<<<1, 64, 0, stream>>>((const unsigned short*)d_in[0], flag);
  k_convert<<<2048, 256, 0, stream>>>(ca, flag, conv, totalConv);
  k_f2b<<<1024, 256, 0, stream>>>(fv[0], xbf, N * GIN);
  {
    const float* Ws[6] = {fv[1], fv[2], fv[8], fv[9], fv[15], fv[16]};
    const int    Ks[6] = {GIN, GIN, CDIM, CDIM, CDIM, CDIM};
    for (int i = 0; i < 6; i++)
      k_transpose_bf<<<dim3(CDIM/32, Ks[i]/32), dim3(32, 8), 0, stream>>>(Ws[i], Wt[i], Ks[i]);
  }

  // ---- CSR by dst (payload = src) ----
  hipMemsetAsync(deg, 0, (size_t)N * 4, stream);
  k_count<<<(E + 255)/256, 256, 0, stream>>>(edst, E, deg);
  k_scan<<<1, 256, 0, stream>>>(deg, off, cur);
  k_fill<<<(E + 255)/256, 256, 0, stream>>>(esrc, edst, E, cur, srcs);

  // ---- 3 GATv2 + GraphNorm + ReLU layers ----
  const float* att_[3] = {fv[3],  fv[10], fv[17]};
  const float* b_[3]   = {fv[4],  fv[11], fv[18]};
  const float* gw_[3]  = {fv[5],  fv[12], fv[19]};
  const float* gb_[3]  = {fv[6],  fv[13], fv[20]};
  const float* gm_[3]  = {fv[7],  fv[14], fv[21]};

  const __hip_bfloat16* inbuf = xbf;
  int K = GIN;
  for (int layer = 0; layer < 3; layer++){
    k_gemm_mfma<<<dim3(N/128, CDIM/128, 2), 256, 0, stream>>>(
        inbuf, Wt[layer*2], Wt[layer*2 + 1], XL, XR, K);
    if (layer < 2){
      k_fused_attn<1><<<N/4, 256, 0, stream>>>(XL, XR, att_[layer], off, srcs, b_[layer], OUT);
      k_graphnorm_relu<<<NGRAPH, 256, 0, stream>>>(OUT, gw_[layer], gb_[layer], gm_[layer], HBbf, CDIM);
    } else {
      k_fused_attn<0><<<N/4, 256, 0, stream>>>(XL, XR, att_[layer], off, srcs, b_[layer], OUT);
      k_graphnorm_relu<<<NGRAPH, 64, 0, stream>>>(OUT, gw_[layer], gb_[layer], gm_[layer], HBbf, FDIM);
    }
    inbuf = HBbf;
    K = CDIM;
  }

  // ---- pool + linear ----
  k_pool_linear<<<NGRAPH, 64, 0, stream>>>(HBbf, fv[22], fv[23], d_out, flag);
}

// Round 4
// 483.137 us; speedup vs baseline: 3.1224x; 1.2636x over previous
//
#include <hip/hip_runtime.h>
#include <hip/hip_bf16.h>
#include <stdint.h>
#include <string.h>

#define NNODES 16384
#define GIN 256      // input feature dim
#define NG 64        // nodes per graph (N/G)
#define NGRAPH 256
#define FDIM 64      // per-head out dim
#define CDIM 512     // H*F

typedef __attribute__((ext_vector_type(8))) short bf16x8;
typedef __attribute__((ext_vector_type(4))) float f32x4;

__device__ __forceinline__ float bf2f(unsigned short u){
  union { unsigned int i; float f; } w; w.i = ((unsigned int)u) << 16; return w.f;
}

__device__ __forceinline__ void async16(const void* g, void* l){
  __builtin_amdgcn_global_load_lds(
      (const __attribute__((address_space(1))) unsigned int*)g,
      (__attribute__((address_space(3))) unsigned int*)l, 16, 0, 0);
}

// ---------- dtype detection: fp32 low-halves look like garbage bf16 ----------
__global__ void k_detect(const unsigned short* __restrict__ x, int* __restrict__ flag){
  int lane = threadIdx.x;  // 64 threads
  int bad = 0;
  #pragma unroll
  for (int j = 0; j < 4; j++){
    float f = bf2f(x[lane*4 + j]);
    if (!(fabsf(f) < 1e4f)) bad++;   // catches huge and NaN
  }
  #pragma unroll
  for (int o = 32; o; o >>= 1) bad += __shfl_down(bad, o);
  if (lane == 0) *flag = (bad > 16) ? 1 : 0;   // 1 = inputs are fp32
}

// ---------- convert all float inputs to canonical fp32 (+ bf16 copy of x) ----------
struct CArgs {
  const void* p[24];
  int cum[25];
};

__global__ void k_convert(CArgs a, const int* __restrict__ flag, float* __restrict__ dst,
                          __hip_bfloat16* __restrict__ xbf, int total){
  int isf32 = *flag;
  for (int idx = blockIdx.x*blockDim.x + threadIdx.x; idx < total; idx += gridDim.x*blockDim.x){
    int seg = 0;
    while (idx >= a.cum[seg+1]) seg++;
    int off = idx - a.cum[seg];
    float v;
    if (isf32) v = ((const float*)a.p[seg])[off];
    else       v = bf2f(((const unsigned short*)a.p[seg])[off]);
    dst[idx] = v;
    if (seg == 0) xbf[off] = __float2bfloat16(v);
  }
}

// ---------- W[K x 512] fp32 -> Wt[512 x K] bf16 (transpose) ----------
__global__ void k_transpose_bf(const float* __restrict__ W, __hip_bfloat16* __restrict__ Wt, int K){
  __shared__ float t[32][33];
  int n0 = blockIdx.x*32, k0 = blockIdx.y*32;
  for (int r = threadIdx.y; r < 32; r += 8)
    t[r][threadIdx.x] = W[(size_t)(k0 + r)*CDIM + n0 + threadIdx.x];
  __syncthreads();
  for (int r = threadIdx.y; r < 32; r += 8)
    Wt[(size_t)(n0 + r)*K + k0 + threadIdx.x] = __float2bfloat16(t[threadIdx.x][r]);
}

// ---------- CSR build (by dst), payload = src node ----------
__global__ void k_count(const int* __restrict__ edst, int E, int* __restrict__ deg){
  int e = blockIdx.x*blockDim.x + threadIdx.x;
  if (e < E) atomicAdd(&deg[edst[e]], 1);
}

__global__ void k_scan(const int* __restrict__ deg, int* __restrict__ off, int* __restrict__ cur){
  __shared__ int ss[256];
  int t = threadIdx.x;
  int base = t * 64;
  int s = 0;
  for (int j = 0; j < 64; j++) s += deg[base + j];
  ss[t] = s;
  __syncthreads();
  for (int o = 1; o < 256; o <<= 1){
    int v = 0;
    if (t >= o) v = ss[t - o];
    __syncthreads();
    if (t >= o) ss[t] += v;
    __syncthreads();
  }
  int run = ss[t] - s;  // exclusive prefix
  for (int j = 0; j < 64; j++){
    int i = base + j;
    off[i] = run;
    cur[i] = run;
    run += deg[i];
  }
  if (t == 255) off[NNODES] = run;
}

__global__ void k_fill(const int* __restrict__ esrc, const int* __restrict__ edst, int E,
                       int* __restrict__ cur, int* __restrict__ srcs){
  int e = blockIdx.x*blockDim.x + threadIdx.x;
  if (e < E){
    int pos = atomicAdd(&cur[edst[e]], 1);
    srcs[pos] = esrc[e];
  }
}

// ---------- bf16 MFMA GEMM: C[N x 512] = A[N x K] * Wt^T, Wl and Wr via grid.z ----------
__global__ __launch_bounds__(256) void k_gemm_mfma(
    const __hip_bfloat16* __restrict__ A,
    const __hip_bfloat16* __restrict__ Wtl, const __hip_bfloat16* __restrict__ Wtr,
    float* __restrict__ Cl, float* __restrict__ Cr, int K){
  const __hip_bfloat16* Wt = blockIdx.z ? Wtr : Wtl;
  float*                C  = blockIdx.z ? Cr  : Cl;
  __shared__ __align__(16) char As[8192];  // [c:4][m:128] 16B chunks
  __shared__ __align__(16) char Bs[8192];  // [c:4][n:128] 16B chunks
  int tid = threadIdx.x;
  int w = tid >> 6, lane = tid & 63;
  int wm = w >> 1, wn = w & 1;
  int row0 = blockIdx.x * 128, col0 = blockIdx.y * 128;
  int c = lane >> 4, l16 = lane & 15;

  f32x4 acc[4][4];
  #pragma unroll
  for (int i = 0; i < 4; i++)
    #pragma unroll
    for (int j = 0; j < 4; j++) acc[i][j] = (f32x4){0.f,0.f,0.f,0.f};

  for (int k0 = 0; k0 < K; k0 += 32){
    #pragma unroll
    for (int t = 0; t < 4; t++){
      int call = t*4 + w;             // wave-uniform
      if (call < 8){
        int cc = call >> 1, half = call & 1;
        const __hip_bfloat16* gp = A + (size_t)(row0 + half*64 + lane)*K + k0 + cc*8;
        async16(gp, As + call*1024);
      } else {
        int q = call - 8;
        int cc = q >> 1, half = q & 1;
        const __hip_bfloat16* gp = Wt + (size_t)(col0 + half*64 + lane)*K + k0 + cc*8;
        async16(gp, Bs + q*1024);
      }
    }
    __syncthreads();
    bf16x8 af[4], bfr[4];
    #pragma unroll
    for (int i = 0; i < 4; i++)
      af[i]  = *(const bf16x8*)(As + c*2048 + (wm*64 + i*16 + l16)*16);
    #pragma unroll
    for (int j = 0; j < 4; j++)
      bfr[j] = *(const bf16x8*)(Bs + c*2048 + (wn*64 + j*16 + l16)*16);
    #pragma unroll
    for (int i = 0; i < 4; i++)
      #pragma unroll
      for (int j = 0; j < 4; j++)
        acc[i][j] = __builtin_amdgcn_mfma_f32_16x16x32_bf16(af[i], bfr[j], acc[i][j], 0, 0, 0);
    __syncthreads();
  }

  int r4 = lane >> 4;
  #pragma unroll
  for (int i = 0; i < 4; i++)
    #pragma unroll
    for (int j = 0; j < 4; j++){
      float* cp = C + (size_t)(row0 + wm*64 + i*16 + r4*4)*CDIM + col0 + wn*64 + j*16 + l16;
      #pragma unroll
      for (int r = 0; r < 4; r++)
        cp[(size_t)r*CDIM] = acc[i][j][r];
    }
}

// ---------- fused GATv2 edge phase, lane = (head, feature-octet) ----------
// lane = h*8 + f8; lane owns features f = f8*8 + j (j=0..7) of head h.
// channel index c = h*64 + f8*8 + j = lane*8 + j  -> all loads/stores contiguous.
template<int CONCAT>
__global__ __launch_bounds__(256) void k_fused_attn(
    const float* __restrict__ XL, const float* __restrict__ XR, const float* __restrict__ att,
    const int* __restrict__ off, const int* __restrict__ srcs,
    const float* __restrict__ bias, float* __restrict__ OUT){
  int wave = threadIdx.x >> 6, lane = threadIdx.x & 63;
  int d = blockIdx.x * 4 + wave;
  if (d >= NNODES) return;

  const float4* xrp = (const float4*)(XR + (size_t)d*CDIM + lane*8);
  float4 xr0 = xrp[0], xr1 = xrp[1];
  const float4* atp = (const float4*)(att + lane*8);
  float4 at0 = atp[0], at1 = atp[1];

  float acc[8];
  #pragma unroll
  for (int j = 0; j < 8; j++) acc[j] = 0.f;
  float den = 0.f;

  int beg = off[d], end = off[d+1];

  auto leaky = [](float m){ return fmaxf(m, 0.2f*m); };

  for (int i = beg; i < end; i += 2){
    int s0 = srcs[i];
    bool two = (i + 1 < end);
    int s1 = two ? srcs[i+1] : s0;
    const float4* p0 = (const float4*)(XL + (size_t)s0*CDIM + lane*8);
    const float4* p1 = (const float4*)(XL + (size_t)s1*CDIM + lane*8);
    float4 a0 = p0[0], a1 = p0[1];
    float4 b0 = p1[0], b1 = p1[1];

    // edge 0
    {
      float v;
      v  = leaky(a0.x + xr0.x) * at0.x;
      v += leaky(a0.y + xr0.y) * at0.y;
      v += leaky(a0.z + xr0.z) * at0.z;
      v += leaky(a0.w + xr0.w) * at0.w;
      v += leaky(a1.x + xr1.x) * at1.x;
      v += leaky(a1.y + xr1.y) * at1.y;
      v += leaky(a1.z + xr1.z) * at1.z;
      v += leaky(a1.w + xr1.w) * at1.w;
      v += __shfl_xor(v, 1); v += __shfl_xor(v, 2); v += __shfl_xor(v, 4);
      float p = expf(v);
      den += p;
      acc[0] = fmaf(p, a0.x, acc[0]); acc[1] = fmaf(p, a0.y, acc[1]);
      acc[2] = fmaf(p, a0.z, acc[2]); acc[3] = fmaf(p, a0.w, acc[3]);
      acc[4] = fmaf(p, a1.x, acc[4]); acc[5] = fmaf(p, a1.y, acc[5]);
      acc[6] = fmaf(p, a1.z, acc[6]); acc[7] = fmaf(p, a1.w, acc[7]);
    }
    // edge 1
    if (two){
      float v;
      v  = leaky(b0.x + xr0.x) * at0.x;
      v += leaky(b0.y + xr0.y) * at0.y;
      v += leaky(b0.z + xr0.z) * at0.z;
      v += leaky(b0.w + xr0.w) * at0.w;
      v += leaky(b1.x + xr1.x) * at1.x;
      v += leaky(b1.y + xr1.y) * at1.y;
      v += leaky(b1.z + xr1.z) * at1.z;
      v += leaky(b1.w + xr1.w) * at1.w;
      v += __shfl_xor(v, 1); v += __shfl_xor(v, 2); v += __shfl_xor(v, 4);
      float p = expf(v);
      den += p;
      acc[0] = fmaf(p, b0.x, acc[0]); acc[1] = fmaf(p, b0.y, acc[1]);
      acc[2] = fmaf(p, b0.z, acc[2]); acc[3] = fmaf(p, b0.w, acc[3]);
      acc[4] = fmaf(p, b1.x, acc[4]); acc[5] = fmaf(p, b1.y, acc[5]);
      acc[6] = fmaf(p, b1.z, acc[6]); acc[7] = fmaf(p, b1.w, acc[7]);
    }
  }

  float inv = 1.f / (den + 1e-16f);
  const float4* bp = (const float4*)(bias + (CONCAT ? lane*8 : (lane & 7)*8));

  if (CONCAT){
    float4 b0v = bp[0], b1v = bp[1];
    float4 o0 = {acc[0]*inv + b0v.x, acc[1]*inv + b0v.y, acc[2]*inv + b0v.z, acc[3]*inv + b0v.w};
    float4 o1 = {acc[4]*inv + b1v.x, acc[5]*inv + b1v.y, acc[6]*inv + b1v.z, acc[7]*inv + b1v.w};
    float4* op = (float4*)(OUT + (size_t)d*CDIM + lane*8);
    op[0] = o0; op[1] = o1;
  } else {
    float r[8];
    #pragma unroll
    for (int j = 0; j < 8; j++) r[j] = acc[j] * inv;
    #pragma unroll
    for (int o = 8; o < 64; o <<= 1)
      #pragma unroll
      for (int j = 0; j < 8; j++) r[j] += __shfl_xor(r[j], o);
    if (lane < 8){
      float4 b0v = bp[0], b1v = bp[1];
      float4 o0 = {r[0]*0.125f + b0v.x, r[1]*0.125f + b0v.y, r[2]*0.125f + b0v.z, r[3]*0.125f + b0v.w};
      float4 o1 = {r[4]*0.125f + b1v.x, r[5]*0.125f + b1v.y, r[6]*0.125f + b1v.z, r[7]*0.125f + b1v.w};
      float4* op = (float4*)(OUT + (size_t)d*FDIM + lane*8);
      op[0] = o0; op[1] = o1;
    }
  }
}

// ---------- GraphNorm + ReLU -> bf16 (nodes of graph g are rows g*64 .. g*64+63) ----------
__global__ void k_graphnorm_relu(const float* __restrict__ X, const float* __restrict__ w,
    const float* __restrict__ b, const float* __restrict__ ms,
    __hip_bfloat16* __restrict__ Y, int C){
  int g = blockIdx.x;
  const float* xg = X + (long)g * NG * C;
  __hip_bfloat16* yg = Y + (long)g * NG * C;
  for (int c = threadIdx.x; c < C; c += blockDim.x){
    float s1 = 0.f, s2 = 0.f;
    for (int i = 0; i < NG; i++){
      float v = xg[(long)i*C + c];
      s1 += v; s2 += v*v;
    }
    float mean = s1 * (1.f/NG);
    float m = ms[c];
    float var = s2 * (1.f/NG) - 2.f*m*mean*mean + m*m*mean*mean;
    float inv = rsqrtf(var + 1e-5f);
    float ww = w[c], bb = b[c];
    for (int i = 0; i < NG; i++){
      float v = xg[(long)i*C + c];
      float y = fmaf(ww * (v - m*mean), inv, bb);
      yg[(long)i*C + c] = __float2bfloat16(y > 0.f ? y : 0.f);
    }
  }
}

// ---------- global mean pool + linear [64 -> 2], dtype-flag-aware output ----------
__global__ void k_pool_linear(const __hip_bfloat16* __restrict__ H, const float* __restrict__ Wlin,
    const float* __restrict__ blin, void* out, const int* __restrict__ flag){
  int g = blockIdx.x, c = threadIdx.x;  // 64 threads
  float s = 0.f;
  for (int i = 0; i < NG; i++) s += __bfloat162float(H[(long)(g*NG + i)*FDIM + c]);
  float pooled = s * (1.f/NG);
  float v0 = pooled * Wlin[c*2 + 0];
  float v1 = pooled * Wlin[c*2 + 1];
  #pragma unroll
  for (int o = 32; o; o >>= 1){ v0 += __shfl_down(v0, o); v1 += __shfl_down(v1, o); }
  if (c == 0){
    float o0 = v0 + blin[0], o1 = v1 + blin[1];
    if (*flag){
      ((float*)out)[g*2 + 0] = o0;
      ((float*)out)[g*2 + 1] = o1;
    } else {
      ((__hip_bfloat16*)out)[g*2 + 0] = __float2bfloat16(o0);
      ((__hip_bfloat16*)out)[g*2 + 1] = __float2bfloat16(o1);
    }
  }
}

extern "C" void kernel_launch(void* const* d_in, const int* in_sizes, int n_in,
                              void* d_out, int out_size, void* d_ws, size_t ws_size,
                              hipStream_t stream){
  const int N = NNODES;
  const int E = in_sizes[1];

  const int* esrc = (const int*)d_in[1];
  const int* edst = (const int*)d_in[2];

  // ---- workspace layout ----
  char* ws = (char*)d_ws;
  size_t cursor_b = 0;
  auto alloc = [&](size_t bytes)->char*{
    char* p = ws + cursor_b;
    cursor_b += (bytes + 255) & ~size_t(255);
    return p;
  };

  int* flag = (int*)alloc(256);

  static const int convIdx[24] = {0,4,5,6,7,8,9,10,11,12,13,14,15,16,17,18,19,20,21,22,23,24,25,26};
  CArgs ca;
  int cums[25]; cums[0] = 0;
  for (int i = 0; i < 24; i++){
    ca.p[i] = d_in[convIdx[i]];
    cums[i+1] = cums[i] + in_sizes[convIdx[i]];
  }
  memcpy(ca.cum, cums, sizeof(cums));
  int totalConv = cums[24];

  float* conv = (float*)alloc((size_t)totalConv * 4);
  const float* fv[24];
  for (int i = 0; i < 24; i++) fv[i] = conv + cums[i];
  // fv map: 0:x 1:Wl1 2:Wr1 3:att1 4:b1 5:gnw1 6:gnb1 7:gnm1
  //         8:Wl2 9:Wr2 10:att2 11:b2 12:gnw2 13:gnb2 14:gnm2
  //         15:Wl3 16:Wr3 17:att3 18:b3 19:gnw3 20:gnb3 21:gnm3 22:Wlin 23:blin

  float* XL  = (float*)alloc((size_t)N * CDIM * 4);
  float* XR  = (float*)alloc((size_t)N * CDIM * 4);   // fused OUT aliases XR (row-local)
  __hip_bfloat16* HBbf = (__hip_bfloat16*)alloc((size_t)N * CDIM * 2);
  __hip_bfloat16* xbf  = (__hip_bfloat16*)alloc((size_t)N * GIN * 2);
  __hip_bfloat16* Wt[6];
  Wt[0] = (__hip_bfloat16*)alloc((size_t)CDIM * GIN * 2);
  Wt[1] = (__hip_bfloat16*)alloc((size_t)CDIM * GIN * 2);
  Wt[2] = (__hip_bfloat16*)alloc((size_t)CDIM * CDIM * 2);
  Wt[3] = (__hip_bfloat16*)alloc((size_t)CDIM * CDIM * 2);
  Wt[4] = (__hip_bfloat16*)alloc((size_t)CDIM * CDIM * 2);
  Wt[5] = (__hip_bfloat16*)alloc((size_t)CDIM * CDIM * 2);
  int* deg  = (int*)alloc((size_t)N * 4);
  int* off  = (int*)alloc((size_t)(N + 1) * 4);
  int* cur  = (int*)alloc((size_t)N * 4);
  int* srcs = (int*)alloc((size_t)E * 4);
  float* OUT = XR;

  // ---- dtype detect + convert ----
  k_detect<<<1, 64, 0, stream>>>((const unsigned short*)d_in[0], flag);
  k_convert<<<2048, 256, 0, stream>>>(ca, flag, conv, xbf, totalConv);
  {
    const float* Ws[6] = {fv[1], fv[2], fv[8], fv[9], fv[15], fv[16]};
    const int    Ks[6] = {GIN, GIN, CDIM, CDIM, CDIM, CDIM};
    for (int i = 0; i < 6; i++)
      k_transpose_bf<<<dim3(CDIM/32, Ks[i]/32), dim3(32, 8), 0, stream>>>(Ws[i], Wt[i], Ks[i]);
  }

  // ---- CSR by dst (payload = src) ----
  hipMemsetAsync(deg, 0, (size_t)N * 4, stream);
  k_count<<<(E + 255)/256, 256, 0, stream>>>(edst, E, deg);
  k_scan<<<1, 256, 0, stream>>>(deg, off, cur);
  k_fill<<<(E + 255)/256, 256, 0, stream>>>(esrc, edst, E, cur, srcs);

  // ---- 3 GATv2 + GraphNorm + ReLU layers ----
  const float* att_[3] = {fv[3],  fv[10], fv[17]};
  const float* b_[3]   = {fv[4],  fv[11], fv[18]};
  const float* gw_[3]  = {fv[5],  fv[12], fv[19]};
  const float* gb_[3]  = {fv[6],  fv[13], fv[20]};
  const float* gm_[3]  = {fv[7],  fv[14], fv[21]};

  const __hip_bfloat16* inbuf = xbf;
  int K = GIN;
  for (int layer = 0; layer < 3; layer++){
    k_gemm_mfma<<<dim3(N/128, CDIM/128, 2), 256, 0, stream>>>(
        inbuf, Wt[layer*2], Wt[layer*2 + 1], XL, XR, K);
    if (layer < 2){
      k_fused_attn<1><<<N/4, 256, 0, stream>>>(XL, XR, att_[layer], off, srcs, b_[layer], OUT);
      k_graphnorm_relu<<<NGRAPH, 256, 0, stream>>>(OUT, gw_[layer], gb_[layer], gm_[layer], HBbf, CDIM);
    } else {
      k_fused_attn<0><<<N/4, 256, 0, stream>>>(XL, XR, att_[layer], off, srcs, b_[layer], OUT);
      k_graphnorm_relu<<<NGRAPH, 64, 0, stream>>>(OUT, gw_[layer], gb_[layer], gm_[layer], HBbf, FDIM);
    }
    inbuf = HBbf;
    K = CDIM;
  }

  // ---- pool + linear ----
  k_pool_linear<<<NGRAPH, 64, 0, stream>>>(HBbf, fv[22], fv[23], d_out, flag);
}

// Round 5
// 432.823 us; speedup vs baseline: 3.4853x; 1.1162x over previous
//
#include <hip/hip_runtime.h>
#include <hip/hip_bf16.h>
#include <stdint.h>
#include <string.h>

#define NNODES 16384
#define GIN 256      // input feature dim
#define NG 64        // nodes per graph (N/G)
#define NGRAPH 256
#define FDIM 64      // per-head out dim
#define CDIM 512     // H*F

typedef __attribute__((ext_vector_type(8))) short bf16x8;
typedef __attribute__((ext_vector_type(4))) float f32x4;

__device__ __forceinline__ float bf2f(unsigned short u){
  union { unsigned int i; float f; } w; w.i = ((unsigned int)u) << 16; return w.f;
}

// unpack two bf16 packed in a uint to two floats
__device__ __forceinline__ void unpk(unsigned int u, float& lo, float& hi){
  union { unsigned int i; float f; } a, b;
  a.i = u << 16; b.i = u & 0xffff0000u;
  lo = a.f; hi = b.f;
}

__device__ __forceinline__ void async16(const void* g, void* l){
  __builtin_amdgcn_global_load_lds(
      (const __attribute__((address_space(1))) unsigned int*)g,
      (__attribute__((address_space(3))) unsigned int*)l, 16, 0, 0);
}

// ---------- dtype detection: fp32 low-halves look like garbage bf16 ----------
__global__ void k_detect(const unsigned short* __restrict__ x, int* __restrict__ flag){
  int lane = threadIdx.x;  // 64 threads
  int bad = 0;
  #pragma unroll
  for (int j = 0; j < 4; j++){
    float f = bf2f(x[lane*4 + j]);
    if (!(fabsf(f) < 1e4f)) bad++;   // catches huge and NaN
  }
  #pragma unroll
  for (int o = 32; o; o >>= 1) bad += __shfl_down(bad, o);
  if (lane == 0) *flag = (bad > 16) ? 1 : 0;   // 1 = inputs are fp32
}

// ---------- convert all float inputs to canonical fp32 (+ bf16 copy of x) ----------
struct CArgs {
  const void* p[24];
  int cum[25];
};

__global__ void k_convert(CArgs a, const int* __restrict__ flag, float* __restrict__ dst,
                          __hip_bfloat16* __restrict__ xbf, int total){
  int isf32 = *flag;
  for (int idx = blockIdx.x*blockDim.x + threadIdx.x; idx < total; idx += gridDim.x*blockDim.x){
    int seg = 0;
    while (idx >= a.cum[seg+1]) seg++;
    int off = idx - a.cum[seg];
    float v;
    if (isf32) v = ((const float*)a.p[seg])[off];
    else       v = bf2f(((const unsigned short*)a.p[seg])[off]);
    dst[idx] = v;
    if (seg == 0) xbf[off] = __float2bfloat16(v);
  }
}

// ---------- W[K x 512] fp32 -> Wt[512 x K] bf16 (transpose) ----------
__global__ void k_transpose_bf(const float* __restrict__ W, __hip_bfloat16* __restrict__ Wt, int K){
  __shared__ float t[32][33];
  int n0 = blockIdx.x*32, k0 = blockIdx.y*32;
  for (int r = threadIdx.y; r < 32; r += 8)
    t[r][threadIdx.x] = W[(size_t)(k0 + r)*CDIM + n0 + threadIdx.x];
  __syncthreads();
  for (int r = threadIdx.y; r < 32; r += 8)
    Wt[(size_t)(n0 + r)*K + k0 + threadIdx.x] = __float2bfloat16(t[threadIdx.x][r]);
}

// ---------- CSR build (by dst), payload = src node ----------
__global__ void k_count(const int* __restrict__ edst, int E, int* __restrict__ deg){
  int e = blockIdx.x*blockDim.x + threadIdx.x;
  if (e < E) atomicAdd(&deg[edst[e]], 1);
}

__global__ void k_scan(const int* __restrict__ deg, int* __restrict__ off, int* __restrict__ cur){
  __shared__ int ss[256];
  int t = threadIdx.x;
  int base = t * 64;
  int s = 0;
  for (int j = 0; j < 64; j++) s += deg[base + j];
  ss[t] = s;
  __syncthreads();
  for (int o = 1; o < 256; o <<= 1){
    int v = 0;
    if (t >= o) v = ss[t - o];
    __syncthreads();
    if (t >= o) ss[t] += v;
    __syncthreads();
  }
  int run = ss[t] - s;  // exclusive prefix
  for (int j = 0; j < 64; j++){
    int i = base + j;
    off[i] = run;
    cur[i] = run;
    run += deg[i];
  }
  if (t == 255) off[NNODES] = run;
}

__global__ void k_fill(const int* __restrict__ esrc, const int* __restrict__ edst, int E,
                       int* __restrict__ cur, int* __restrict__ srcs){
  int e = blockIdx.x*blockDim.x + threadIdx.x;
  if (e < E){
    int pos = atomicAdd(&cur[edst[e]], 1);
    srcs[pos] = esrc[e];
  }
}

// ---------- bf16 MFMA GEMM: z=0 -> XLbf (bf16 out), z=1 -> XR (fp32 out) ----------
__global__ __launch_bounds__(256) void k_gemm_mfma(
    const __hip_bfloat16* __restrict__ A,
    const __hip_bfloat16* __restrict__ Wtl, const __hip_bfloat16* __restrict__ Wtr,
    __hip_bfloat16* __restrict__ Clbf, float* __restrict__ Cr, int K){
  const __hip_bfloat16* Wt = blockIdx.z ? Wtr : Wtl;
  __shared__ __align__(16) char As[8192];  // [c:4][m:128] 16B chunks
  __shared__ __align__(16) char Bs[8192];  // [c:4][n:128] 16B chunks
  int tid = threadIdx.x;
  int w = tid >> 6, lane = tid & 63;
  int wm = w >> 1, wn = w & 1;
  int row0 = blockIdx.x * 128, col0 = blockIdx.y * 128;
  int c = lane >> 4, l16 = lane & 15;

  f32x4 acc[4][4];
  #pragma unroll
  for (int i = 0; i < 4; i++)
    #pragma unroll
    for (int j = 0; j < 4; j++) acc[i][j] = (f32x4){0.f,0.f,0.f,0.f};

  for (int k0 = 0; k0 < K; k0 += 32){
    #pragma unroll
    for (int t = 0; t < 4; t++){
      int call = t*4 + w;             // wave-uniform
      if (call < 8){
        int cc = call >> 1, half = call & 1;
        const __hip_bfloat16* gp = A + (size_t)(row0 + half*64 + lane)*K + k0 + cc*8;
        async16(gp, As + call*1024);
      } else {
        int q = call - 8;
        int cc = q >> 1, half = q & 1;
        const __hip_bfloat16* gp = Wt + (size_t)(col0 + half*64 + lane)*K + k0 + cc*8;
        async16(gp, Bs + q*1024);
      }
    }
    __syncthreads();
    bf16x8 af[4], bfr[4];
    #pragma unroll
    for (int i = 0; i < 4; i++)
      af[i]  = *(const bf16x8*)(As + c*2048 + (wm*64 + i*16 + l16)*16);
    #pragma unroll
    for (int j = 0; j < 4; j++)
      bfr[j] = *(const bf16x8*)(Bs + c*2048 + (wn*64 + j*16 + l16)*16);
    #pragma unroll
    for (int i = 0; i < 4; i++)
      #pragma unroll
      for (int j = 0; j < 4; j++)
        acc[i][j] = __builtin_amdgcn_mfma_f32_16x16x32_bf16(af[i], bfr[j], acc[i][j], 0, 0, 0);
    __syncthreads();
  }

  int r4 = lane >> 4;
  if (blockIdx.z == 0){
    #pragma unroll
    for (int i = 0; i < 4; i++)
      #pragma unroll
      for (int j = 0; j < 4; j++){
        __hip_bfloat16* cp = Clbf + (size_t)(row0 + wm*64 + i*16 + r4*4)*CDIM + col0 + wn*64 + j*16 + l16;
        #pragma unroll
        for (int r = 0; r < 4; r++)
          cp[(size_t)r*CDIM] = __float2bfloat16(acc[i][j][r]);
      }
  } else {
    #pragma unroll
    for (int i = 0; i < 4; i++)
      #pragma unroll
      for (int j = 0; j < 4; j++){
        float* cp = Cr + (size_t)(row0 + wm*64 + i*16 + r4*4)*CDIM + col0 + wn*64 + j*16 + l16;
        #pragma unroll
        for (int r = 0; r < 4; r++)
          cp[(size_t)r*CDIM] = acc[i][j][r];
      }
  }
}

// ---------- fused GATv2 edge phase, lane = (head, feature-octet), bf16 XL gather ----------
// lane = h*8 + f8; lane owns channels c = lane*8 + j (j=0..7) -> contiguous 16B bf16 per lane.
template<int CONCAT>
__global__ __launch_bounds__(256) void k_fused_attn(
    const __hip_bfloat16* __restrict__ XL, const float* __restrict__ XR, const float* __restrict__ att,
    const int* __restrict__ off, const int* __restrict__ srcs,
    const float* __restrict__ bias, float* __restrict__ OUT){
  int wave = threadIdx.x >> 6, lane = threadIdx.x & 63;
  int d = blockIdx.x * 4 + wave;
  if (d >= NNODES) return;

  const float4* xrp = (const float4*)(XR + (size_t)d*CDIM + lane*8);
  float4 xr0 = xrp[0], xr1 = xrp[1];
  float xr[8] = {xr0.x, xr0.y, xr0.z, xr0.w, xr1.x, xr1.y, xr1.z, xr1.w};
  const float4* atp = (const float4*)(att + lane*8);
  float4 at0 = atp[0], at1 = atp[1];
  float at[8] = {at0.x, at0.y, at0.z, at0.w, at1.x, at1.y, at1.z, at1.w};

  float acc[8];
  #pragma unroll
  for (int j = 0; j < 8; j++) acc[j] = 0.f;
  float den = 0.f;

  int beg = off[d], end = off[d+1];

  auto leaky = [](float m){ return fmaxf(m, 0.2f*m); };

  for (int i = beg; i < end; i += 4){
    int n = end - i;                       // wave-uniform
    int s0 = srcs[i];
    int s1 = n > 1 ? srcs[i+1] : s0;
    int s2 = n > 2 ? srcs[i+2] : s0;
    int s3 = n > 3 ? srcs[i+3] : s0;
    uint4 rw[4];
    rw[0] = *(const uint4*)((const char*)XL + ((size_t)s0*CDIM + lane*8)*2);
    rw[1] = *(const uint4*)((const char*)XL + ((size_t)s1*CDIM + lane*8)*2);
    rw[2] = *(const uint4*)((const char*)XL + ((size_t)s2*CDIM + lane*8)*2);
    rw[3] = *(const uint4*)((const char*)XL + ((size_t)s3*CDIM + lane*8)*2);

    #pragma unroll
    for (int e = 0; e < 4; e++){
      if (e < n){                          // wave-uniform branch
        float xv[8];
        unpk(rw[e].x, xv[0], xv[1]);
        unpk(rw[e].y, xv[2], xv[3]);
        unpk(rw[e].z, xv[4], xv[5]);
        unpk(rw[e].w, xv[6], xv[7]);
        float v = 0.f;
        #pragma unroll
        for (int j = 0; j < 8; j++) v = fmaf(leaky(xv[j] + xr[j]), at[j], v);
        v += __shfl_xor(v, 1); v += __shfl_xor(v, 2); v += __shfl_xor(v, 4);
        float p = expf(v);
        den += p;
        #pragma unroll
        for (int j = 0; j < 8; j++) acc[j] = fmaf(p, xv[j], acc[j]);
      }
    }
  }

  float inv = 1.f / (den + 1e-16f);
  const float4* bp = (const float4*)(bias + (CONCAT ? lane*8 : (lane & 7)*8));

  if (CONCAT){
    float4 b0v = bp[0], b1v = bp[1];
    float4 o0 = {acc[0]*inv + b0v.x, acc[1]*inv + b0v.y, acc[2]*inv + b0v.z, acc[3]*inv + b0v.w};
    float4 o1 = {acc[4]*inv + b1v.x, acc[5]*inv + b1v.y, acc[6]*inv + b1v.z, acc[7]*inv + b1v.w};
    float4* op = (float4*)(OUT + (size_t)d*CDIM + lane*8);
    op[0] = o0; op[1] = o1;
  } else {
    float r[8];
    #pragma unroll
    for (int j = 0; j < 8; j++) r[j] = acc[j] * inv;
    #pragma unroll
    for (int o = 8; o < 64; o <<= 1)
      #pragma unroll
      for (int j = 0; j < 8; j++) r[j] += __shfl_xor(r[j], o);
    if (lane < 8){
      float4 b0v = bp[0], b1v = bp[1];
      float4 o0 = {r[0]*0.125f + b0v.x, r[1]*0.125f + b0v.y, r[2]*0.125f + b0v.z, r[3]*0.125f + b0v.w};
      float4 o1 = {r[4]*0.125f + b1v.x, r[5]*0.125f + b1v.y, r[6]*0.125f + b1v.z, r[7]*0.125f + b1v.w};
      float4* op = (float4*)(OUT + (size_t)d*FDIM + lane*8);
      op[0] = o0; op[1] = o1;
    }
  }
}

// ---------- GraphNorm + ReLU -> bf16 (nodes of graph g are rows g*64 .. g*64+63) ----------
__global__ void k_graphnorm_relu(const float* __restrict__ X, const float* __restrict__ w,
    const float* __restrict__ b, const float* __restrict__ ms,
    __hip_bfloat16* __restrict__ Y, int C){
  int g = blockIdx.x;
  const float* xg = X + (long)g * NG * C;
  __hip_bfloat16* yg = Y + (long)g * NG * C;
  for (int c = threadIdx.x; c < C; c += blockDim.x){
    float s1 = 0.f, s2 = 0.f;
    for (int i = 0; i < NG; i++){
      float v = xg[(long)i*C + c];
      s1 += v; s2 += v*v;
    }
    float mean = s1 * (1.f/NG);
    float m = ms[c];
    float var = s2 * (1.f/NG) - 2.f*m*mean*mean + m*m*mean*mean;
    float inv = rsqrtf(var + 1e-5f);
    float ww = w[c], bb = b[c];
    for (int i = 0; i < NG; i++){
      float v = xg[(long)i*C + c];
      float y = fmaf(ww * (v - m*mean), inv, bb);
      yg[(long)i*C + c] = __float2bfloat16(y > 0.f ? y : 0.f);
    }
  }
}

// ---------- global mean pool + linear [64 -> 2], dtype-flag-aware output ----------
__global__ void k_pool_linear(const __hip_bfloat16* __restrict__ H, const float* __restrict__ Wlin,
    const float* __restrict__ blin, void* out, const int* __restrict__ flag){
  int g = blockIdx.x, c = threadIdx.x;  // 64 threads
  float s = 0.f;
  for (int i = 0; i < NG; i++) s += __bfloat162float(H[(long)(g*NG + i)*FDIM + c]);
  float pooled = s * (1.f/NG);
  float v0 = pooled * Wlin[c*2 + 0];
  float v1 = pooled * Wlin[c*2 + 1];
  #pragma unroll
  for (int o = 32; o; o >>= 1){ v0 += __shfl_down(v0, o); v1 += __shfl_down(v1, o); }
  if (c == 0){
    float o0 = v0 + blin[0], o1 = v1 + blin[1];
    if (*flag){
      ((float*)out)[g*2 + 0] = o0;
      ((float*)out)[g*2 + 1] = o1;
    } else {
      ((__hip_bfloat16*)out)[g*2 + 0] = __float2bfloat16(o0);
      ((__hip_bfloat16*)out)[g*2 + 1] = __float2bfloat16(o1);
    }
  }
}

extern "C" void kernel_launch(void* const* d_in, const int* in_sizes, int n_in,
                              void* d_out, int out_size, void* d_ws, size_t ws_size,
                              hipStream_t stream){
  const int N = NNODES;
  const int E = in_sizes[1];

  const int* esrc = (const int*)d_in[1];
  const int* edst = (const int*)d_in[2];

  // ---- workspace layout ----
  char* ws = (char*)d_ws;
  size_t cursor_b = 0;
  auto alloc = [&](size_t bytes)->char*{
    char* p = ws + cursor_b;
    cursor_b += (bytes + 255) & ~size_t(255);
    return p;
  };

  int* flag = (int*)alloc(256);

  static const int convIdx[24] = {0,4,5,6,7,8,9,10,11,12,13,14,15,16,17,18,19,20,21,22,23,24,25,26};
  CArgs ca;
  int cums[25]; cums[0] = 0;
  for (int i = 0; i < 24; i++){
    ca.p[i] = d_in[convIdx[i]];
    cums[i+1] = cums[i] + in_sizes[convIdx[i]];
  }
  memcpy(ca.cum, cums, sizeof(cums));
  int totalConv = cums[24];

  float* conv = (float*)alloc((size_t)totalConv * 4);
  const float* fv[24];
  for (int i = 0; i < 24; i++) fv[i] = conv + cums[i];
  // fv map: 0:x 1:Wl1 2:Wr1 3:att1 4:b1 5:gnw1 6:gnb1 7:gnm1
  //         8:Wl2 9:Wr2 10:att2 11:b2 12:gnw2 13:gnb2 14:gnm2
  //         15:Wl3 16:Wr3 17:att3 18:b3 19:gnw3 20:gnb3 21:gnm3 22:Wlin 23:blin

  __hip_bfloat16* XLbf = (__hip_bfloat16*)alloc((size_t)N * CDIM * 2);
  float* XR  = (float*)alloc((size_t)N * CDIM * 4);   // fused OUT aliases XR (row-local, layers 1-2)
  float* OUT3 = (float*)alloc((size_t)N * FDIM * 4);  // layer-3 output (separate: no alias race)
  __hip_bfloat16* HBbf = (__hip_bfloat16*)alloc((size_t)N * CDIM * 2);
  __hip_bfloat16* xbf  = (__hip_bfloat16*)alloc((size_t)N * GIN * 2);
  __hip_bfloat16* Wt[6];
  Wt[0] = (__hip_bfloat16*)alloc((size_t)CDIM * GIN * 2);
  Wt[1] = (__hip_bfloat16*)alloc((size_t)CDIM * GIN * 2);
  Wt[2] = (__hip_bfloat16*)alloc((size_t)CDIM * CDIM * 2);
  Wt[3] = (__hip_bfloat16*)alloc((size_t)CDIM * CDIM * 2);
  Wt[4] = (__hip_bfloat16*)alloc((size_t)CDIM * CDIM * 2);
  Wt[5] = (__hip_bfloat16*)alloc((size_t)CDIM * CDIM * 2);
  int* deg  = (int*)alloc((size_t)N * 4);
  int* off  = (int*)alloc((size_t)(N + 1) * 4);
  int* cur  = (int*)alloc((size_t)N * 4);
  int* srcs = (int*)alloc((size_t)E * 4);
  float* OUT = XR;

  // ---- dtype detect + convert ----
  k_detect<<<1, 64, 0, stream>>>((const unsigned short*)d_in[0], flag);
  k_convert<<<2048, 256, 0, stream>>>(ca, flag, conv, xbf, totalConv);
  {
    const float* Ws[6] = {fv[1], fv[2], fv[8], fv[9], fv[15], fv[16]};
    const int    Ks[6] = {GIN, GIN, CDIM, CDIM, CDIM, CDIM};
    for (int i = 0; i < 6; i++)
      k_transpose_bf<<<dim3(CDIM/32, Ks[i]/32), dim3(32, 8), 0, stream>>>(Ws[i], Wt[i], Ks[i]);
  }

  // ---- CSR by dst (payload = src) ----
  hipMemsetAsync(deg, 0, (size_t)N * 4, stream);
  k_count<<<(E + 255)/256, 256, 0, stream>>>(edst, E, deg);
  k_scan<<<1, 256, 0, stream>>>(deg, off, cur);
  k_fill<<<(E + 255)/256, 256, 0, stream>>>(esrc, edst, E, cur, srcs);

  // ---- 3 GATv2 + GraphNorm + ReLU layers ----
  const float* att_[3] = {fv[3],  fv[10], fv[17]};
  const float* b_[3]   = {fv[4],  fv[11], fv[18]};
  const float* gw_[3]  = {fv[5],  fv[12], fv[19]};
  const float* gb_[3]  = {fv[6],  fv[13], fv[20]};
  const float* gm_[3]  = {fv[7],  fv[14], fv[21]};

  const __hip_bfloat16* inbuf = xbf;
  int K = GIN;
  for (int layer = 0; layer < 3; layer++){
    k_gemm_mfma<<<dim3(N/128, CDIM/128, 2), 256, 0, stream>>>(
        inbuf, Wt[layer*2], Wt[layer*2 + 1], XLbf, XR, K);
    if (layer < 2){
      k_fused_attn<1><<<N/4, 256, 0, stream>>>(XLbf, XR, att_[layer], off, srcs, b_[layer], OUT);
      k_graphnorm_relu<<<NGRAPH, 256, 0, stream>>>(OUT, gw_[layer], gb_[layer], gm_[layer], HBbf, CDIM);
    } else {
      k_fused_attn<0><<<N/4, 256, 0, stream>>>(XLbf, XR, att_[layer], off, srcs, b_[layer], OUT3);
      k_graphnorm_relu<<<NGRAPH, 64, 0, stream>>>(OUT3, gw_[layer], gb_[layer], gm_[layer], HBbf, FDIM);
    }
    inbuf = HBbf;
    K = CDIM;
  }

  // ---- pool + linear ----
  k_pool_linear<<<NGRAPH, 64, 0, stream>>>(HBbf, fv[22], fv[23], d_out, flag);
}

// Round 7
// 403.658 us; speedup vs baseline: 3.7372x; 1.0723x over previous
//
#include <hip/hip_runtime.h>
#include <hip/hip_bf16.h>
#include <stdint.h>
#include <string.h>

#define NNODES 16384
#define GIN 256      // input feature dim
#define NG 64        // nodes per graph (N/G)
#define NGRAPH 256
#define FDIM 64      // per-head out dim
#define CDIM 512     // H*F

typedef __attribute__((ext_vector_type(8))) short bf16x8;
typedef __attribute__((ext_vector_type(4))) float f32x4;

__device__ __forceinline__ float bf2f(unsigned short u){
  union { unsigned int i; float f; } w; w.i = ((unsigned int)u) << 16; return w.f;
}

// unpack two bf16 packed in a uint to two floats
__device__ __forceinline__ void unpk(unsigned int u, float& lo, float& hi){
  union { unsigned int i; float f; } a, b;
  a.i = u << 16; b.i = u & 0xffff0000u;
  lo = a.f; hi = b.f;
}

union PK8 { __hip_bfloat16 h[8]; uint4 v; };

__device__ __forceinline__ void async16(const void* g, void* l){
  __builtin_amdgcn_global_load_lds(
      (const __attribute__((address_space(1))) unsigned int*)g,
      (__attribute__((address_space(3))) unsigned int*)l, 16, 0, 0);
}

// ---------- dtype detection: fp32 low-halves look like garbage bf16 ----------
__global__ void k_detect(const unsigned short* __restrict__ x, int* __restrict__ flag){
  int lane = threadIdx.x;  // 64 threads
  int bad = 0;
  #pragma unroll
  for (int j = 0; j < 4; j++){
    float f = bf2f(x[lane*4 + j]);
    if (!(fabsf(f) < 1e4f)) bad++;   // catches huge and NaN
  }
  #pragma unroll
  for (int o = 32; o; o >>= 1) bad += __shfl_down(bad, o);
  if (lane == 0) *flag = (bad > 16) ? 1 : 0;   // 1 = inputs are fp32
}

// ---------- convert all float inputs to fp32 (+ bf16 copy of x, + zero deg) ----------
struct CArgs {
  const void* p[24];
  int cum[25];
};

__global__ void k_convert(CArgs a, const int* __restrict__ flag, float* __restrict__ dst,
                          __hip_bfloat16* __restrict__ xbf, int* __restrict__ deg, int total){
  int isf32 = *flag;
  for (int idx = blockIdx.x*blockDim.x + threadIdx.x; idx < total; idx += gridDim.x*blockDim.x){
    if (idx < NNODES) deg[idx] = 0;
    int seg = 0;
    while (idx >= a.cum[seg+1]) seg++;
    int off = idx - a.cum[seg];
    float v;
    if (isf32) v = ((const float*)a.p[seg])[off];
    else       v = bf2f(((const unsigned short*)a.p[seg])[off]);
    dst[idx] = v;
    if (seg == 0) xbf[off] = __float2bfloat16(v);
  }
}

// ---------- merged transpose: 6 × (W[K x 512] fp32 -> Wt[512 x K] bf16) ----------
struct TArgs {
  const float* W[6];
  __hip_bfloat16* Wt[6];
  int K[6];
};

__global__ void k_transpose_all(TArgs t){
  int seg = blockIdx.z;
  int K = t.K[seg];
  int n0 = blockIdx.x*32, k0 = blockIdx.y*32;
  if (k0 >= K) return;
  const float* W = t.W[seg];
  __hip_bfloat16* Wt = t.Wt[seg];
  __shared__ float tl[32][33];
  for (int r = threadIdx.y; r < 32; r += 8)
    tl[r][threadIdx.x] = W[(size_t)(k0 + r)*CDIM + n0 + threadIdx.x];
  __syncthreads();
  for (int r = threadIdx.y; r < 32; r += 8)
    Wt[(size_t)(n0 + r)*K + k0 + threadIdx.x] = __float2bfloat16(tl[threadIdx.x][r]);
}

// ---------- CSR build (by dst), payload = src node ----------
__global__ void k_count(const int* __restrict__ edst, int E, int* __restrict__ deg){
  int e = blockIdx.x*blockDim.x + threadIdx.x;
  if (e < E) atomicAdd(&deg[edst[e]], 1);
}

__global__ void k_scan(const int* __restrict__ deg, int* __restrict__ off, int* __restrict__ cur){
  __shared__ int ss[256];
  int t = threadIdx.x;
  int base = t * 64;
  int s = 0;
  for (int j = 0; j < 64; j++) s += deg[base + j];
  ss[t] = s;
  __syncthreads();
  for (int o = 1; o < 256; o <<= 1){
    int v = 0;
    if (t >= o) v = ss[t - o];
    __syncthreads();
    if (t >= o) ss[t] += v;
    __syncthreads();
  }
  int run = ss[t] - s;  // exclusive prefix
  for (int j = 0; j < 64; j++){
    int i = base + j;
    off[i] = run;
    cur[i] = run;
    run += deg[i];
  }
  if (t == 255) off[NNODES] = run;
}

__global__ void k_fill(const int* __restrict__ esrc, const int* __restrict__ edst, int E,
                       int* __restrict__ cur, int* __restrict__ srcs){
  int e = blockIdx.x*blockDim.x + threadIdx.x;
  if (e < E){
    int pos = atomicAdd(&cur[edst[e]], 1);
    srcs[pos] = esrc[e];
  }
}

// ---------- bf16 MFMA GEMM, BK=64: z=0 -> XLbf, z=1 -> XRbf (both bf16 out) ----------
__global__ __launch_bounds__(256) void k_gemm_mfma(
    const __hip_bfloat16* __restrict__ A,
    const __hip_bfloat16* __restrict__ Wtl, const __hip_bfloat16* __restrict__ Wtr,
    __hip_bfloat16* __restrict__ Cl, __hip_bfloat16* __restrict__ Cr, int K){
  const __hip_bfloat16* Wt = blockIdx.z ? Wtr : Wtl;
  __hip_bfloat16*       C  = blockIdx.z ? Cr  : Cl;
  __shared__ __align__(16) char As[16384];  // [c:8][m:128] 16B chunks (BK=64)
  __shared__ __align__(16) char Bs[16384];  // [c:8][n:128] 16B chunks
  int tid = threadIdx.x;
  int w = tid >> 6, lane = tid & 63;
  int wm = w >> 1, wn = w & 1;
  int row0 = blockIdx.x * 128, col0 = blockIdx.y * 128;
  int c = lane >> 4, l16 = lane & 15;

  f32x4 acc[4][4];
  #pragma unroll
  for (int i = 0; i < 4; i++)
    #pragma unroll
    for (int j = 0; j < 4; j++) acc[i][j] = (f32x4){0.f,0.f,0.f,0.f};

  for (int k0 = 0; k0 < K; k0 += 64){
    // stage 32 KB: 16 A-calls + 16 B-calls, 8 per wave, 1024B each
    #pragma unroll
    for (int t = 0; t < 8; t++){
      int call = t*4 + w;             // wave-uniform 0..31
      if (call < 16){
        int cc = call >> 1, half = call & 1;
        const __hip_bfloat16* gp = A + (size_t)(row0 + half*64 + lane)*K + k0 + cc*8;
        async16(gp, As + call*1024);
      } else {
        int q = call - 16;
        int cc = q >> 1, half = q & 1;
        const __hip_bfloat16* gp = Wt + (size_t)(col0 + half*64 + lane)*K + k0 + cc*8;
        async16(gp, Bs + q*1024);
      }
    }
    __syncthreads();
    #pragma unroll
    for (int ko = 0; ko < 2; ko++){
      bf16x8 af[4], bfr[4];
      #pragma unroll
      for (int i = 0; i < 4; i++)
        af[i]  = *(const bf16x8*)(As + (ko*4 + c)*2048 + (wm*64 + i*16 + l16)*16);
      #pragma unroll
      for (int j = 0; j < 4; j++)
        bfr[j] = *(const bf16x8*)(Bs + (ko*4 + c)*2048 + (wn*64 + j*16 + l16)*16);
      #pragma unroll
      for (int i = 0; i < 4; i++)
        #pragma unroll
        for (int j = 0; j < 4; j++)
          acc[i][j] = __builtin_amdgcn_mfma_f32_16x16x32_bf16(af[i], bfr[j], acc[i][j], 0, 0, 0);
    }
    __syncthreads();
  }

  int r4 = lane >> 4;
  #pragma unroll
  for (int i = 0; i < 4; i++)
    #pragma unroll
    for (int j = 0; j < 4; j++){
      __hip_bfloat16* cp = C + (size_t)(row0 + wm*64 + i*16 + r4*4)*CDIM + col0 + wn*64 + j*16 + l16;
      #pragma unroll
      for (int r = 0; r < 4; r++)
        cp[(size_t)r*CDIM] = __float2bfloat16(acc[i][j][r]);
    }
}

// ---------- fused GATv2 edge phase, lane = (head, feature-octet), all-bf16 I/O ----------
// lane = h*8 + f8; lane owns channels c = lane*8 + j (j=0..7) -> contiguous 16B bf16 per lane.
template<int CONCAT>
__global__ __launch_bounds__(256) void k_fused_attn(
    const __hip_bfloat16* __restrict__ XL, const __hip_bfloat16* __restrict__ XR,
    const float* __restrict__ att,
    const int* __restrict__ off, const int* __restrict__ srcs,
    const float* __restrict__ bias, __hip_bfloat16* __restrict__ OUT){
  int wave = threadIdx.x >> 6, lane = threadIdx.x & 63;
  int d = blockIdx.x * 4 + wave;
  if (d >= NNODES) return;

  uint4 xru = *(const uint4*)((const char*)XR + ((size_t)d*CDIM + lane*8)*2);
  float xr[8];
  unpk(xru.x, xr[0], xr[1]); unpk(xru.y, xr[2], xr[3]);
  unpk(xru.z, xr[4], xr[5]); unpk(xru.w, xr[6], xr[7]);
  const float4* atp = (const float4*)(att + lane*8);
  float4 at0 = atp[0], at1 = atp[1];
  float at[8] = {at0.x, at0.y, at0.z, at0.w, at1.x, at1.y, at1.z, at1.w};

  float acc[8];
  #pragma unroll
  for (int j = 0; j < 8; j++) acc[j] = 0.f;
  float den = 0.f;

  int beg = off[d], end = off[d+1];

  auto leaky = [](float m){ return fmaxf(m, 0.2f*m); };

  for (int i = beg; i < end; i += 4){
    int n = end - i;                       // wave-uniform
    int s0 = srcs[i];
    int s1 = n > 1 ? srcs[i+1] : s0;
    int s2 = n > 2 ? srcs[i+2] : s0;
    int s3 = n > 3 ? srcs[i+3] : s0;
    uint4 rw[4];
    rw[0] = *(const uint4*)((const char*)XL + ((size_t)s0*CDIM + lane*8)*2);
    rw[1] = *(const uint4*)((const char*)XL + ((size_t)s1*CDIM + lane*8)*2);
    rw[2] = *(const uint4*)((const char*)XL + ((size_t)s2*CDIM + lane*8)*2);
    rw[3] = *(const uint4*)((const char*)XL + ((size_t)s3*CDIM + lane*8)*2);

    #pragma unroll
    for (int e = 0; e < 4; e++){
      if (e < n){                          // wave-uniform branch
        float xv[8];
        unpk(rw[e].x, xv[0], xv[1]);
        unpk(rw[e].y, xv[2], xv[3]);
        unpk(rw[e].z, xv[4], xv[5]);
        unpk(rw[e].w, xv[6], xv[7]);
        float v = 0.f;
        #pragma unroll
        for (int j = 0; j < 8; j++) v = fmaf(leaky(xv[j] + xr[j]), at[j], v);
        v += __shfl_xor(v, 1); v += __shfl_xor(v, 2); v += __shfl_xor(v, 4);
        float p = expf(v);
        den += p;
        #pragma unroll
        for (int j = 0; j < 8; j++) acc[j] = fmaf(p, xv[j], acc[j]);
      }
    }
  }

  float inv = 1.f / (den + 1e-16f);
  const float4* bp = (const float4*)(bias + (CONCAT ? lane*8 : (lane & 7)*8));

  if (CONCAT){
    float4 b0v = bp[0], b1v = bp[1];
    float bb[8] = {b0v.x, b0v.y, b0v.z, b0v.w, b1v.x, b1v.y, b1v.z, b1v.w};
    PK8 pk;
    #pragma unroll
    for (int j = 0; j < 8; j++)
      pk.h[j] = __float2bfloat16(acc[j]*inv + bb[j]);
    *(uint4*)((char*)OUT + ((size_t)d*CDIM + lane*8)*2) = pk.v;
  } else {
    float r[8];
    #pragma unroll
    for (int j = 0; j < 8; j++) r[j] = acc[j] * inv;
    #pragma unroll
    for (int o = 8; o < 64; o <<= 1)
      #pragma unroll
      for (int j = 0; j < 8; j++) r[j] += __shfl_xor(r[j], o);
    if (lane < 8){
      float4 b0v = bp[0], b1v = bp[1];
      float bb[8] = {b0v.x, b0v.y, b0v.z, b0v.w, b1v.x, b1v.y, b1v.z, b1v.w};
      PK8 pk;
      #pragma unroll
      for (int j = 0; j < 8; j++)
        pk.h[j] = __float2bfloat16(r[j]*0.125f + bb[j]);
      *(uint4*)((char*)OUT + ((size_t)d*FDIM + lane*8)*2) = pk.v;
    }
  }
}

// ---------- GraphNorm + ReLU, bf16 in -> bf16 out (graph g = rows g*64 .. g*64+63) ----------
__global__ void k_graphnorm_relu(const __hip_bfloat16* __restrict__ X, const float* __restrict__ w,
    const float* __restrict__ b, const float* __restrict__ ms,
    __hip_bfloat16* __restrict__ Y, int C){
  int g = blockIdx.x;
  const __hip_bfloat16* xg = X + (long)g * NG * C;
  __hip_bfloat16* yg = Y + (long)g * NG * C;
  for (int c = threadIdx.x; c < C; c += blockDim.x){
    float s1 = 0.f, s2 = 0.f;
    for (int i = 0; i < NG; i++){
      float v = __bfloat162float(xg[(long)i*C + c]);
      s1 += v; s2 += v*v;
    }
    float mean = s1 * (1.f/NG);
    float m = ms[c];
    float var = s2 * (1.f/NG) - 2.f*m*mean*mean + m*m*mean*mean;
    float inv = rsqrtf(var + 1e-5f);
    float ww = w[c], bb = b[c];
    for (int i = 0; i < NG; i++){
      float v = __bfloat162float(xg[(long)i*C + c]);
      float y = fmaf(ww * (v - m*mean), inv, bb);
      yg[(long)i*C + c] = __float2bfloat16(y > 0.f ? y : 0.f);
    }
  }
}

// ---------- global mean pool + linear [64 -> 2], dtype-flag-aware output ----------
__global__ void k_pool_linear(const __hip_bfloat16* __restrict__ H, const float* __restrict__ Wlin,
    const float* __restrict__ blin, void* out, const int* __restrict__ flag){
  int g = blockIdx.x, c = threadIdx.x;  // 64 threads
  float s = 0.f;
  for (int i = 0; i < NG; i++) s += __bfloat162float(H[(long)(g*NG + i)*FDIM + c]);
  float pooled = s * (1.f/NG);
  float v0 = pooled * Wlin[c*2 + 0];
  float v1 = pooled * Wlin[c*2 + 1];
  #pragma unroll
  for (int o = 32; o; o >>= 1){ v0 += __shfl_down(v0, o); v1 += __shfl_down(v1, o); }
  if (c == 0){
    float o0 = v0 + blin[0], o1 = v1 + blin[1];
    if (*flag){
      ((float*)out)[g*2 + 0] = o0;
      ((float*)out)[g*2 + 1] = o1;
    } else {
      ((__hip_bfloat16*)out)[g*2 + 0] = __float2bfloat16(o0);
      ((__hip_bfloat16*)out)[g*2 + 1] = __float2bfloat16(o1);
    }
  }
}

extern "C" void kernel_launch(void* const* d_in, const int* in_sizes, int n_in,
                              void* d_out, int out_size, void* d_ws, size_t ws_size,
                              hipStream_t stream){
  const int N = NNODES;
  const int E = in_sizes[1];

  const int* esrc = (const int*)d_in[1];
  const int* edst = (const int*)d_in[2];

  // ---- workspace layout ----
  char* ws = (char*)d_ws;
  size_t cursor_b = 0;
  auto alloc = [&](size_t bytes)->char*{
    char* p = ws + cursor_b;
    cursor_b += (bytes + 255) & ~size_t(255);
    return p;
  };

  int* flag = (int*)alloc(256);

  static const int convIdx[24] = {0,4,5,6,7,8,9,10,11,12,13,14,15,16,17,18,19,20,21,22,23,24,25,26};
  CArgs ca;
  int cums[25]; cums[0] = 0;
  for (int i = 0; i < 24; i++){
    ca.p[i] = d_in[convIdx[i]];
    cums[i+1] = cums[i] + in_sizes[convIdx[i]];
  }
  memcpy(ca.cum, cums, sizeof(cums));
  int totalConv = cums[24];

  float* conv = (float*)alloc((size_t)totalConv * 4);
  const float* fv[24];
  for (int i = 0; i < 24; i++) fv[i] = conv + cums[i];
  // fv map: 0:x 1:Wl1 2:Wr1 3:att1 4:b1 5:gnw1 6:gnb1 7:gnm1
  //         8:Wl2 9:Wr2 10:att2 11:b2 12:gnw2 13:gnb2 14:gnm2
  //         15:Wl3 16:Wr3 17:att3 18:b3 19:gnw3 20:gnb3 21:gnm3 22:Wlin 23:blin

  __hip_bfloat16* XLbf  = (__hip_bfloat16*)alloc((size_t)N * CDIM * 2);
  __hip_bfloat16* XRbf  = (__hip_bfloat16*)alloc((size_t)N * CDIM * 2);
  __hip_bfloat16* OUTbf = (__hip_bfloat16*)alloc((size_t)N * CDIM * 2);   // attn out, pre-norm
  __hip_bfloat16* OUT3  = (__hip_bfloat16*)alloc((size_t)N * FDIM * 2);
  __hip_bfloat16* HBbf  = (__hip_bfloat16*)alloc((size_t)N * CDIM * 2);
  __hip_bfloat16* xbf   = (__hip_bfloat16*)alloc((size_t)N * GIN * 2);
  __hip_bfloat16* Wt[6];
  Wt[0] = (__hip_bfloat16*)alloc((size_t)CDIM * GIN * 2);
  Wt[1] = (__hip_bfloat16*)alloc((size_t)CDIM * GIN * 2);
  Wt[2] = (__hip_bfloat16*)alloc((size_t)CDIM * CDIM * 2);
  Wt[3] = (__hip_bfloat16*)alloc((size_t)CDIM * CDIM * 2);
  Wt[4] = (__hip_bfloat16*)alloc((size_t)CDIM * CDIM * 2);
  Wt[5] = (__hip_bfloat16*)alloc((size_t)CDIM * CDIM * 2);
  int* deg  = (int*)alloc((size_t)N * 4);
  int* off  = (int*)alloc((size_t)(N + 1) * 4);
  int* cur  = (int*)alloc((size_t)N * 4);
  int* srcs = (int*)alloc((size_t)E * 4);

  // ---- dtype detect + convert (+ deg zero) ----
  k_detect<<<1, 64, 0, stream>>>((const unsigned short*)d_in[0], flag);
  k_convert<<<2048, 256, 0, stream>>>(ca, flag, conv, xbf, deg, totalConv);
  {
    TArgs ta;
    const float* Ws[6] = {fv[1], fv[2], fv[8], fv[9], fv[15], fv[16]};
    const int    Ks[6] = {GIN, GIN, CDIM, CDIM, CDIM, CDIM};
    for (int i = 0; i < 6; i++){ ta.W[i] = Ws[i]; ta.Wt[i] = Wt[i]; ta.K[i] = Ks[i]; }
    k_transpose_all<<<dim3(CDIM/32, CDIM/32, 6), dim3(32, 8), 0, stream>>>(ta);
  }

  // ---- CSR by dst (payload = src) ----
  k_count<<<(E + 255)/256, 256, 0, stream>>>(edst, E, deg);
  k_scan<<<1, 256, 0, stream>>>(deg, off, cur);
  k_fill<<<(E + 255)/256, 256, 0, stream>>>(esrc, edst, E, cur, srcs);

  // ---- 3 GATv2 + GraphNorm + ReLU layers ----
  const float* att_[3] = {fv[3],  fv[10], fv[17]};
  const float* b_[3]   = {fv[4],  fv[11], fv[18]};
  const float* gw_[3]  = {fv[5],  fv[12], fv[19]};
  const float* gb_[3]  = {fv[6],  fv[13], fv[20]};
  const float* gm_[3]  = {fv[7],  fv[14], fv[21]};

  const __hip_bfloat16* inbuf = xbf;
  int K = GIN;
  for (int layer = 0; layer < 3; layer++){
    k_gemm_mfma<<<dim3(N/128, CDIM/128, 2), 256, 0, stream>>>(
        inbuf, Wt[layer*2], Wt[layer*2 + 1], XLbf, XRbf, K);
    if (layer < 2){
      k_fused_attn<1><<<N/4, 256, 0, stream>>>(XLbf, XRbf, att_[layer], off, srcs, b_[layer], OUTbf);
      k_graphnorm_relu<<<NGRAPH, 256, 0, stream>>>(OUTbf, gw_[layer], gb_[layer], gm_[layer], HBbf, CDIM);
    } else {
      k_fused_attn<0><<<N/4, 256, 0, stream>>>(XLbf, XRbf, att_[layer], off, srcs, b_[layer], OUT3);
      k_graphnorm_relu<<<NGRAPH, 64, 0, stream>>>(OUT3, gw_[layer], gb_[layer], gm_[layer], HBbf, FDIM);
    }
    inbuf = HBbf;
    K = CDIM;
  }

  // ---- pool + linear ----
  k_pool_linear<<<NGRAPH, 64, 0, stream>>>(HBbf, fv[22], fv[23], d_out, flag);
}

// Round 8
// 396.536 us; speedup vs baseline: 3.8043x; 1.0180x over previous
//
#include <hip/hip_runtime.h>
#include <hip/hip_bf16.h>
#include <stdint.h>
#include <string.h>

#define NNODES 16384
#define GIN 256      // input feature dim
#define NG 64        // nodes per graph (N/G)
#define NGRAPH 256
#define FDIM 64      // per-head out dim
#define CDIM 512     // H*F

typedef __attribute__((ext_vector_type(8))) short bf16x8;
typedef __attribute__((ext_vector_type(4))) float f32x4;

__device__ __forceinline__ float bf2f(unsigned short u){
  union { unsigned int i; float f; } w; w.i = ((unsigned int)u) << 16; return w.f;
}

// unpack two bf16 packed in a uint to two floats
__device__ __forceinline__ void unpk(unsigned int u, float& lo, float& hi){
  union { unsigned int i; float f; } a, b;
  a.i = u << 16; b.i = u & 0xffff0000u;
  lo = a.f; hi = b.f;
}

union PK8 { __hip_bfloat16 h[8]; uint4 v; };

__device__ __forceinline__ void async16(const void* g, void* l){
  __builtin_amdgcn_global_load_lds(
      (const __attribute__((address_space(1))) unsigned int*)g,
      (__attribute__((address_space(3))) unsigned int*)l, 16, 0, 0);
}

// ---------- dtype detection: fp32 low-halves look like garbage bf16 ----------
__global__ void k_detect(const unsigned short* __restrict__ x, int* __restrict__ flag){
  int lane = threadIdx.x;  // 64 threads
  int bad = 0;
  #pragma unroll
  for (int j = 0; j < 4; j++){
    float f = bf2f(x[lane*4 + j]);
    if (!(fabsf(f) < 1e4f)) bad++;   // catches huge and NaN
  }
  #pragma unroll
  for (int o = 32; o; o >>= 1) bad += __shfl_down(bad, o);
  if (lane == 0) *flag = (bad > 16) ? 1 : 0;   // 1 = inputs are fp32
}

// ---------- weights-only conversion to fp32 (23 segments, x excluded) ----------
struct CArgs {
  const void* p[23];
  int cum[24];
};

__global__ void k_convert(CArgs a, const int* __restrict__ flag, float* __restrict__ dst, int total){
  int isf32 = *flag;
  for (int idx = blockIdx.x*blockDim.x + threadIdx.x; idx < total; idx += gridDim.x*blockDim.x){
    int seg = 0;
    while (idx >= a.cum[seg+1]) seg++;
    int off = idx - a.cum[seg];
    float v;
    if (isf32) v = ((const float*)a.p[seg])[off];
    else       v = bf2f(((const unsigned short*)a.p[seg])[off]);
    dst[idx] = v;
  }
}

// ---------- x -> bf16 (flag-dependent source dtype) + zero deg ----------
__global__ void k_xconv(const void* __restrict__ xin, const int* __restrict__ flag,
                        __hip_bfloat16* __restrict__ xbf, int* __restrict__ deg, int total){
  int isf32 = *flag;
  for (int idx = blockIdx.x*blockDim.x + threadIdx.x; idx < total; idx += gridDim.x*blockDim.x){
    if (idx < NNODES) deg[idx] = 0;
    float v;
    if (isf32) v = ((const float*)xin)[idx];
    else       v = bf2f(((const unsigned short*)xin)[idx]);
    xbf[idx] = __float2bfloat16(v);
  }
}

// ---------- merged transpose: 6 × (W[K x 512] fp32 -> Wt[512 x K] bf16) ----------
struct TArgs {
  const float* W[6];
  __hip_bfloat16* Wt[6];
  int K[6];
};

__global__ void k_transpose_all(TArgs t){
  int seg = blockIdx.z;
  int K = t.K[seg];
  int n0 = blockIdx.x*32, k0 = blockIdx.y*32;
  if (k0 >= K) return;
  const float* W = t.W[seg];
  __hip_bfloat16* Wt = t.Wt[seg];
  __shared__ float tl[32][33];
  for (int r = threadIdx.y; r < 32; r += 8)
    tl[r][threadIdx.x] = W[(size_t)(k0 + r)*CDIM + n0 + threadIdx.x];
  __syncthreads();
  for (int r = threadIdx.y; r < 32; r += 8)
    Wt[(size_t)(n0 + r)*K + k0 + threadIdx.x] = __float2bfloat16(tl[threadIdx.x][r]);
}

// ---------- CSR build (by dst), payload = src node ----------
__global__ void k_count(const int* __restrict__ edst, int E, int* __restrict__ deg){
  int e = blockIdx.x*blockDim.x + threadIdx.x;
  if (e < E) atomicAdd(&deg[edst[e]], 1);
}

__global__ void k_scan(const int* __restrict__ deg, int* __restrict__ off, int* __restrict__ cur){
  __shared__ int ss[256];
  int t = threadIdx.x;
  int base = t * 64;
  int s = 0;
  for (int j = 0; j < 64; j++) s += deg[base + j];
  ss[t] = s;
  __syncthreads();
  for (int o = 1; o < 256; o <<= 1){
    int v = 0;
    if (t >= o) v = ss[t - o];
    __syncthreads();
    if (t >= o) ss[t] += v;
    __syncthreads();
  }
  int run = ss[t] - s;  // exclusive prefix
  for (int j = 0; j < 64; j++){
    int i = base + j;
    off[i] = run;
    cur[i] = run;
    run += deg[i];
  }
  if (t == 255) off[NNODES] = run;
}

__global__ void k_fill(const int* __restrict__ esrc, const int* __restrict__ edst, int E,
                       int* __restrict__ cur, int* __restrict__ srcs){
  int e = blockIdx.x*blockDim.x + threadIdx.x;
  if (e < E){
    int pos = atomicAdd(&cur[edst[e]], 1);
    srcs[pos] = esrc[e];
  }
}

// ---------- fused dual bf16 MFMA GEMM, BK=64, 8 waves: A-tile shared by Wl & Wr ----------
// waves 0-3 compute XL tile (2x2 of 64x64), waves 4-7 compute XR tile.
__global__ __launch_bounds__(512) void k_gemm_dual(
    const __hip_bfloat16* __restrict__ A,
    const __hip_bfloat16* __restrict__ Wtl, const __hip_bfloat16* __restrict__ Wtr,
    __hip_bfloat16* __restrict__ Cl, __hip_bfloat16* __restrict__ Cr, int K){
  __shared__ __align__(16) char As [16384];  // [c:8][m:128] 16B chunks (BK=64)
  __shared__ __align__(16) char Bsl[16384];  // [c:8][n:128]
  __shared__ __align__(16) char Bsr[16384];
  int tid = threadIdx.x;
  int w = tid >> 6, lane = tid & 63;
  int wside = w >> 2;            // 0 = L, 1 = R
  int wm = (w >> 1) & 1, wn = w & 1;
  int row0 = blockIdx.x * 128, col0 = blockIdx.y * 128;
  int c = lane >> 4, l16 = lane & 15;

  f32x4 acc[4][4];
  #pragma unroll
  for (int i = 0; i < 4; i++)
    #pragma unroll
    for (int j = 0; j < 4; j++) acc[i][j] = (f32x4){0.f,0.f,0.f,0.f};

  for (int k0 = 0; k0 < K; k0 += 64){
    // stage 48 KB: 16 A + 16 Bl + 16 Br calls, 6 per wave, 1024B each
    #pragma unroll
    for (int t = 0; t < 6; t++){
      int call = t*8 + w;             // wave-uniform 0..47
      if (call < 16){
        int cc = call >> 1, half = call & 1;
        const __hip_bfloat16* gp = A + (size_t)(row0 + half*64 + lane)*K + k0 + cc*8;
        async16(gp, As + call*1024);
      } else if (call < 32){
        int q = call - 16;
        int cc = q >> 1, half = q & 1;
        const __hip_bfloat16* gp = Wtl + (size_t)(col0 + half*64 + lane)*K + k0 + cc*8;
        async16(gp, Bsl + q*1024);
      } else {
        int q = call - 32;
        int cc = q >> 1, half = q & 1;
        const __hip_bfloat16* gp = Wtr + (size_t)(col0 + half*64 + lane)*K + k0 + cc*8;
        async16(gp, Bsr + q*1024);
      }
    }
    __syncthreads();
    const char* Bs = wside ? Bsr : Bsl;
    #pragma unroll
    for (int ko = 0; ko < 2; ko++){
      bf16x8 af[4], bfr[4];
      #pragma unroll
      for (int i = 0; i < 4; i++)
        af[i]  = *(const bf16x8*)(As + (ko*4 + c)*2048 + (wm*64 + i*16 + l16)*16);
      #pragma unroll
      for (int j = 0; j < 4; j++)
        bfr[j] = *(const bf16x8*)(Bs + (ko*4 + c)*2048 + (wn*64 + j*16 + l16)*16);
      #pragma unroll
      for (int i = 0; i < 4; i++)
        #pragma unroll
        for (int j = 0; j < 4; j++)
          acc[i][j] = __builtin_amdgcn_mfma_f32_16x16x32_bf16(af[i], bfr[j], acc[i][j], 0, 0, 0);
    }
    __syncthreads();
  }

  __hip_bfloat16* C = wside ? Cr : Cl;
  int r4 = lane >> 4;
  #pragma unroll
  for (int i = 0; i < 4; i++)
    #pragma unroll
    for (int j = 0; j < 4; j++){
      __hip_bfloat16* cp = C + (size_t)(row0 + wm*64 + i*16 + r4*4)*CDIM + col0 + wn*64 + j*16 + l16;
      #pragma unroll
      for (int r = 0; r < 4; r++)
        cp[(size_t)r*CDIM] = __float2bfloat16(acc[i][j][r]);
    }
}

// ---------- fused GATv2 edge phase, lane = (head, feature-octet), all-bf16 I/O ----------
// lane = h*8 + f8; lane owns channels c = lane*8 + j (j=0..7) -> contiguous 16B bf16 per lane.
template<int CONCAT>
__global__ __launch_bounds__(256) void k_fused_attn(
    const __hip_bfloat16* __restrict__ XL, const __hip_bfloat16* __restrict__ XR,
    const float* __restrict__ att,
    const int* __restrict__ off, const int* __restrict__ srcs,
    const float* __restrict__ bias, __hip_bfloat16* __restrict__ OUT){
  int wave = threadIdx.x >> 6, lane = threadIdx.x & 63;
  int d = blockIdx.x * 4 + wave;
  if (d >= NNODES) return;

  uint4 xru = *(const uint4*)((const char*)XR + ((size_t)d*CDIM + lane*8)*2);
  float xr[8];
  unpk(xru.x, xr[0], xr[1]); unpk(xru.y, xr[2], xr[3]);
  unpk(xru.z, xr[4], xr[5]); unpk(xru.w, xr[6], xr[7]);
  const float4* atp = (const float4*)(att + lane*8);
  float4 at0 = atp[0], at1 = atp[1];
  float at[8] = {at0.x, at0.y, at0.z, at0.w, at1.x, at1.y, at1.z, at1.w};

  float acc[8];
  #pragma unroll
  for (int j = 0; j < 8; j++) acc[j] = 0.f;
  float den = 0.f;

  int beg = off[d], end = off[d+1];

  auto leaky = [](float m){ return fmaxf(m, 0.2f*m); };

  for (int i = beg; i < end; i += 4){
    int n = end - i;                       // wave-uniform
    int s0 = srcs[i];
    int s1 = n > 1 ? srcs[i+1] : s0;
    int s2 = n > 2 ? srcs[i+2] : s0;
    int s3 = n > 3 ? srcs[i+3] : s0;
    uint4 rw[4];
    rw[0] = *(const uint4*)((const char*)XL + ((size_t)s0*CDIM + lane*8)*2);
    rw[1] = *(const uint4*)((const char*)XL + ((size_t)s1*CDIM + lane*8)*2);
    rw[2] = *(const uint4*)((const char*)XL + ((size_t)s2*CDIM + lane*8)*2);
    rw[3] = *(const uint4*)((const char*)XL + ((size_t)s3*CDIM + lane*8)*2);

    #pragma unroll
    for (int e = 0; e < 4; e++){
      if (e < n){                          // wave-uniform branch
        float xv[8];
        unpk(rw[e].x, xv[0], xv[1]);
        unpk(rw[e].y, xv[2], xv[3]);
        unpk(rw[e].z, xv[4], xv[5]);
        unpk(rw[e].w, xv[6], xv[7]);
        float v = 0.f;
        #pragma unroll
        for (int j = 0; j < 8; j++) v = fmaf(leaky(xv[j] + xr[j]), at[j], v);
        v += __shfl_xor(v, 1); v += __shfl_xor(v, 2); v += __shfl_xor(v, 4);
        float p = expf(v);
        den += p;
        #pragma unroll
        for (int j = 0; j < 8; j++) acc[j] = fmaf(p, xv[j], acc[j]);
      }
    }
  }

  float inv = 1.f / (den + 1e-16f);
  const float4* bp = (const float4*)(bias + (CONCAT ? lane*8 : (lane & 7)*8));

  if (CONCAT){
    float4 b0v = bp[0], b1v = bp[1];
    float bb[8] = {b0v.x, b0v.y, b0v.z, b0v.w, b1v.x, b1v.y, b1v.z, b1v.w};
    PK8 pk;
    #pragma unroll
    for (int j = 0; j < 8; j++)
      pk.h[j] = __float2bfloat16(acc[j]*inv + bb[j]);
    *(uint4*)((char*)OUT + ((size_t)d*CDIM + lane*8)*2) = pk.v;
  } else {
    float r[8];
    #pragma unroll
    for (int j = 0; j < 8; j++) r[j] = acc[j] * inv;
    #pragma unroll
    for (int o = 8; o < 64; o <<= 1)
      #pragma unroll
      for (int j = 0; j < 8; j++) r[j] += __shfl_xor(r[j], o);
    if (lane < 8){
      float4 b0v = bp[0], b1v = bp[1];
      float bb[8] = {b0v.x, b0v.y, b0v.z, b0v.w, b1v.x, b1v.y, b1v.z, b1v.w};
      PK8 pk;
      #pragma unroll
      for (int j = 0; j < 8; j++)
        pk.h[j] = __float2bfloat16(r[j]*0.125f + bb[j]);
      *(uint4*)((char*)OUT + ((size_t)d*FDIM + lane*8)*2) = pk.v;
    }
  }
}

// ---------- GraphNorm + ReLU, bf16 in -> bf16 out (graph g = rows g*64 .. g*64+63) ----------
__global__ void k_graphnorm_relu(const __hip_bfloat16* __restrict__ X, const float* __restrict__ w,
    const float* __restrict__ b, const float* __restrict__ ms,
    __hip_bfloat16* __restrict__ Y, int C){
  int g = blockIdx.x;
  const __hip_bfloat16* xg = X + (long)g * NG * C;
  __hip_bfloat16* yg = Y + (long)g * NG * C;
  for (int c = threadIdx.x; c < C; c += blockDim.x){
    float s1 = 0.f, s2 = 0.f;
    for (int i = 0; i < NG; i++){
      float v = __bfloat162float(xg[(long)i*C + c]);
      s1 += v; s2 += v*v;
    }
    float mean = s1 * (1.f/NG);
    float m = ms[c];
    float var = s2 * (1.f/NG) - 2.f*m*mean*mean + m*m*mean*mean;
    float inv = rsqrtf(var + 1e-5f);
    float ww = w[c], bb = b[c];
    for (int i = 0; i < NG; i++){
      float v = __bfloat162float(xg[(long)i*C + c]);
      float y = fmaf(ww * (v - m*mean), inv, bb);
      yg[(long)i*C + c] = __float2bfloat16(y > 0.f ? y : 0.f);
    }
  }
}

// ---------- global mean pool + linear [64 -> 2], dtype-flag-aware output ----------
__global__ void k_pool_linear(const __hip_bfloat16* __restrict__ H, const float* __restrict__ Wlin,
    const float* __restrict__ blin, void* out, const int* __restrict__ flag){
  int g = blockIdx.x, c = threadIdx.x;  // 64 threads
  float s = 0.f;
  for (int i = 0; i < NG; i++) s += __bfloat162float(H[(long)(g*NG + i)*FDIM + c]);
  float pooled = s * (1.f/NG);
  float v0 = pooled * Wlin[c*2 + 0];
  float v1 = pooled * Wlin[c*2 + 1];
  #pragma unroll
  for (int o = 32; o; o >>= 1){ v0 += __shfl_down(v0, o); v1 += __shfl_down(v1, o); }
  if (c == 0){
    float o0 = v0 + blin[0], o1 = v1 + blin[1];
    if (*flag){
      ((float*)out)[g*2 + 0] = o0;
      ((float*)out)[g*2 + 1] = o1;
    } else {
      ((__hip_bfloat16*)out)[g*2 + 0] = __float2bfloat16(o0);
      ((__hip_bfloat16*)out)[g*2 + 1] = __float2bfloat16(o1);
    }
  }
}

extern "C" void kernel_launch(void* const* d_in, const int* in_sizes, int n_in,
                              void* d_out, int out_size, void* d_ws, size_t ws_size,
                              hipStream_t stream){
  const int N = NNODES;
  const int E = in_sizes[1];

  const int* esrc = (const int*)d_in[1];
  const int* edst = (const int*)d_in[2];

  // ---- workspace layout ----
  char* ws = (char*)d_ws;
  size_t cursor_b = 0;
  auto alloc = [&](size_t bytes)->char*{
    char* p = ws + cursor_b;
    cursor_b += (bytes + 255) & ~size_t(255);
    return p;
  };

  int* flag = (int*)alloc(256);

  // weight segments only (input order, x excluded)
  static const int convIdx[23] = {4,5,6,7,8,9,10,11,12,13,14,15,16,17,18,19,20,21,22,23,24,25,26};
  CArgs ca;
  int cums[24]; cums[0] = 0;
  for (int i = 0; i < 23; i++){
    ca.p[i] = d_in[convIdx[i]];
    cums[i+1] = cums[i] + in_sizes[convIdx[i]];
  }
  memcpy(ca.cum, cums, sizeof(cums));
  int totalConv = cums[23];

  float* conv = (float*)alloc((size_t)totalConv * 4);
  const float* fw[23];
  for (int i = 0; i < 23; i++) fw[i] = conv + cums[i];
  // fw map: 0:Wl1 1:Wr1 2:att1 3:b1 4:gnw1 5:gnb1 6:gnm1
  //         7:Wl2 8:Wr2 9:att2 10:b2 11:gnw2 12:gnb2 13:gnm2
  //         14:Wl3 15:Wr3 16:att3 17:b3 18:gnw3 19:gnb3 20:gnm3 21:Wlin 22:blin

  __hip_bfloat16* XLbf  = (__hip_bfloat16*)alloc((size_t)N * CDIM * 2);
  __hip_bfloat16* XRbf  = (__hip_bfloat16*)alloc((size_t)N * CDIM * 2);
  __hip_bfloat16* OUTbf = (__hip_bfloat16*)alloc((size_t)N * CDIM * 2);   // attn out, pre-norm
  __hip_bfloat16* OUT3  = (__hip_bfloat16*)alloc((size_t)N * FDIM * 2);
  __hip_bfloat16* HBbf  = (__hip_bfloat16*)alloc((size_t)N * CDIM * 2);
  __hip_bfloat16* xbf   = (__hip_bfloat16*)alloc((size_t)N * GIN * 2);
  __hip_bfloat16* Wt[6];
  Wt[0] = (__hip_bfloat16*)alloc((size_t)CDIM * GIN * 2);
  Wt[1] = (__hip_bfloat16*)alloc((size_t)CDIM * GIN * 2);
  Wt[2] = (__hip_bfloat16*)alloc((size_t)CDIM * CDIM * 2);
  Wt[3] = (__hip_bfloat16*)alloc((size_t)CDIM * CDIM * 2);
  Wt[4] = (__hip_bfloat16*)alloc((size_t)CDIM * CDIM * 2);
  Wt[5] = (__hip_bfloat16*)alloc((size_t)CDIM * CDIM * 2);
  int* deg  = (int*)alloc((size_t)N * 4);
  int* off  = (int*)alloc((size_t)(N + 1) * 4);
  int* cur  = (int*)alloc((size_t)N * 4);
  int* srcs = (int*)alloc((size_t)E * 4);

  // ---- dtype detect + convert (+ deg zero) ----
  k_detect<<<1, 64, 0, stream>>>((const unsigned short*)d_in[0], flag);
  k_convert<<<512, 256, 0, stream>>>(ca, flag, conv, totalConv);
  k_xconv<<<2048, 256, 0, stream>>>(d_in[0], flag, xbf, deg, N * GIN);
  {
    TArgs ta;
    const float* Ws[6] = {fw[0], fw[1], fw[7], fw[8], fw[14], fw[15]};
    const int    Ks[6] = {GIN, GIN, CDIM, CDIM, CDIM, CDIM};
    for (int i = 0; i < 6; i++){ ta.W[i] = Ws[i]; ta.Wt[i] = Wt[i]; ta.K[i] = Ks[i]; }
    k_transpose_all<<<dim3(CDIM/32, CDIM/32, 6), dim3(32, 8), 0, stream>>>(ta);
  }

  // ---- CSR by dst (payload = src) ----
  k_count<<<(E + 255)/256, 256, 0, stream>>>(edst, E, deg);
  k_scan<<<1, 256, 0, stream>>>(deg, off, cur);
  k_fill<<<(E + 255)/256, 256, 0, stream>>>(esrc, edst, E, cur, srcs);

  // ---- 3 GATv2 + GraphNorm + ReLU layers ----
  const float* att_[3] = {fw[2],  fw[9],  fw[16]};
  const float* b_[3]   = {fw[3],  fw[10], fw[17]};
  const float* gw_[3]  = {fw[4],  fw[11], fw[18]};
  const float* gb_[3]  = {fw[5],  fw[12], fw[19]};
  const float* gm_[3]  = {fw[6],  fw[13], fw[20]};

  const __hip_bfloat16* inbuf = xbf;
  int K = GIN;
  for (int layer = 0; layer < 3; layer++){
    k_gemm_dual<<<dim3(N/128, CDIM/128), 512, 0, stream>>>(
        inbuf, Wt[layer*2], Wt[layer*2 + 1], XLbf, XRbf, K);
    if (layer < 2){
      k_fused_attn<1><<<N/4, 256, 0, stream>>>(XLbf, XRbf, att_[layer], off, srcs, b_[layer], OUTbf);
      k_graphnorm_relu<<<NGRAPH, 256, 0, stream>>>(OUTbf, gw_[layer], gb_[layer], gm_[layer], HBbf, CDIM);
    } else {
      k_fused_attn<0><<<N/4, 256, 0, stream>>>(XLbf, XRbf, att_[layer], off, srcs, b_[layer], OUT3);
      k_graphnorm_relu<<<NGRAPH, 64, 0, stream>>>(OUT3, gw_[layer], gb_[layer], gm_[layer], HBbf, FDIM);
    }
    inbuf = HBbf;
    K = CDIM;
  }

  // ---- pool + linear ----
  k_pool_linear<<<NGRAPH, 64, 0, stream>>>(HBbf, fw[21], fw[22], d_out, flag);
}